// Round 4
// baseline (4050.488 us; speedup 1.0000x reference)
//
#include <hip/hip_runtime.h>
#include <stdint.h>

typedef unsigned long long u64;
typedef unsigned int u32;
typedef unsigned short u16;

#define BATCH 64
#define NN    512
#define NAUG  1024
#define DM    256
#define NEDGE 4096
#define CAP   64
#define LM    400      // Lanczos steps
#define RCAP  28       // CSR entries cached in registers per row

// ---------------- workspace layout (bytes) ----------------
#define OFF_ADJ   ((size_t)0)
#define SZ_ADJ    ((size_t)BATCH*NN*8*8)                 // 2 MiB bitmask
#define OFF_ADJT  (OFF_ADJ + SZ_ADJ)
#define OFF_LAM   (OFF_ADJT + SZ_ADJ)                    // 256 B for lambda
#define OFF_DEGI  (OFF_LAM + 256)
#define OFF_LENS  (OFF_DEGI + (size_t)BATCH*NN*4)
#define OFF_ENTS  (OFF_LENS + (size_t)BATCH*NN*4)
#define OFF_VALS  (OFF_ENTS + (size_t)BATCH*NN*CAP*4)
#define OFF_XF    (OFF_VALS + (size_t)BATCH*NN*CAP*4)    // x fp32 [b,1024,256]
#define OFF_XT1   (OFF_XF  + (size_t)BATCH*NAUG*DM*4)    // t1@x fp32
#define OFF_S     (OFF_XT1 + (size_t)BATCH*NAUG*DM*4)    // pre-relu sums fp32

// ---------------- adjacency scatter (bitmask) ----------------
__global__ void k_scatter(const int* __restrict__ senders, const int* __restrict__ receivers,
                          u64* __restrict__ adj, u64* __restrict__ adjT){
    int idx = blockIdx.x * 256 + threadIdx.x;          // BATCH*NEDGE threads
    int b = idx >> 12;
    int s = senders[idx];
    int r = receivers[idx];
    if (s >= 0){
        atomicOr(&adj [((size_t)b*NN + s)*8 + (r >> 6)], 1ull << (r & 63));
        atomicOr(&adjT[((size_t)b*NN + r)*8 + (s >> 6)], 1ull << (s & 63));
    }
}

// ---------------- degree (exact double 1/sqrt) ----------------
__global__ void k_deg(const u64* __restrict__ adj, const u64* __restrict__ adjT,
                      float* __restrict__ degInv){
    int idx = blockIdx.x * 256 + threadIdx.x;          // BATCH*NN threads
    const u64* a = adj  + (size_t)idx * 8;
    const u64* t = adjT + (size_t)idx * 8;
    int deg = 0;
#pragma unroll
    for (int w = 0; w < 8; ++w) deg += __popcll(a[w] | t[w]);
    degInv[idx] = (float)(1.0 / sqrt((double)(deg < 1 ? 1 : deg)));
}

// ---------------- build CSR of masked lap (fp32 exact; one wave per row) ----------
// entry: bits[8:0]=col j, bit9 = type (0: lap_ij = v real; 1: lap_ij = i*v imag)
__global__ __launch_bounds__(256)
void k_build(const u64* __restrict__ adj, const u64* __restrict__ adjT,
             const float* __restrict__ degInv, const int* __restrict__ n_node,
             u32* __restrict__ ents, float* __restrict__ vals, int* __restrict__ lens){
    int gw   = (blockIdx.x * 256 + threadIdx.x) >> 6;  // global wave = row id
    int lane = threadIdx.x & 63;
    int b = gw >> 9;
    int i = gw & (NN - 1);
    const u64* arow = adj  + ((size_t)b*NN + i)*8;
    const u64* trow = adjT + ((size_t)b*NN + i)*8;
    int wsel = lane >> 3, sh = (lane & 7) * 8;
    u32 ba = (u32)((arow[wsel] >> sh) & 0xFFull);
    u32 bt = (u32)((trow[wsel] >> sh) & 0xFFull);
    int nn_b = n_node[b];
    bool mi  = i < nn_b;
    float di = degInv[b*NN + i];
    int j0 = lane * 8;

    float vr_[8], vi_[8];
    int cnt = 0;
#pragma unroll
    for (int jj = 0; jj < 8; ++jj){
        int j = j0 + jj;
        int a = (ba >> jj) & 1, t = (bt >> jj) & 1;
        bool mm = mi && (j < nn_b);
        float c = di * degInv[b*NN + j];
        float vr = 0.f, vi = 0.f;
        if (j == i){
            if (mm) vr = 1.0f - (a ? c : 0.0f);        // diag: mask*(1 - selfloop*c)
        } else if (mm && ((a | t) != 0)){
            if (a & t)      vr = -c;                   // lap = -c
            else if (a)     vi = -c;                   // lap = -i*c
            else            vi =  c;                   // lap = +i*c
        }
        vr_[jj] = vr; vi_[jj] = vi;
        cnt += (vr != 0.f || vi != 0.f) ? 1 : 0;
    }
    // wave-wide exclusive scan of cnt
    int off = cnt;
#pragma unroll
    for (int d = 1; d < 64; d <<= 1){
        int nb = __shfl_up(off, d);
        if (lane >= d) off += nb;
    }
    int excl = off - cnt;
    int tot  = __shfl(off, 63);
    int p = excl;
    u32*   erow = ents + ((size_t)b*NN + i)*CAP;
    float* vrow = vals + ((size_t)b*NN + i)*CAP;
#pragma unroll
    for (int jj = 0; jj < 8; ++jj){
        float vr = vr_[jj], vi = vi_[jj];
        if (vr != 0.f || vi != 0.f){
            if (p < CAP){
                int ty = (vi != 0.f) ? 1 : 0;
                erow[p] = (u32)(j0 + jj) | ((u32)ty << 9);
                vrow[p] = ty ? vi : vr;
            }
            p++;
        }
    }
    if (lane == 63) lens[b*NN + i] = tot > CAP ? CAP : tot;
}

// ---------------- Lanczos (one block per graph) + Sturm bisection ----------------
// T = tridiag(alpha, beta); Ritz values <= lam_max + O(eps). Gap-independent
// convergence ~ (ln(4n)/2m)^2 -> ~1e-8 at m=400 (power iteration was the R3 bug:
// adversarial-gap error up to ~5%).
__global__ __launch_bounds__(512)
void k_lanczos(const u32* __restrict__ ents, const float* __restrict__ vals,
               const int* __restrict__ lens, float* __restrict__ lam){
    int b = blockIdx.x;
    int i = threadIdx.x;
    int lane = i & 63, wv = i >> 6;
    __shared__ float V1r[NN], V1i[NN];
    __shared__ double alph[LM];
    __shared__ double bet[LM + 1];
    __shared__ float red[8];
    __shared__ float sA, sB;
    int len = lens[b*NN + i];
    const u32*   er = ents + ((size_t)b*NN + i)*CAP;
    const float* ev = vals + ((size_t)b*NN + i)*CAP;
    u32 enR[RCAP]; float evR[RCAP];
#pragma unroll
    for (int e = 0; e < RCAP; ++e){
        bool p = e < len;
        enR[e] = p ? er[e] : 0u;
        evR[e] = p ? ev[e] : 0.f;
    }
    // random init
    u32 h = (u32)i * 2654435761u + 0x9E3779B9u;
    h ^= h >> 16; h *= 0x85EBCA6Bu; h ^= h >> 13;
    float r0 = (float)(h & 0xFFFF) * (1.f/65536.f) - 0.5f;
    h = h * 1664525u + 1013904223u;
    float r1 = (float)(h & 0xFFFF) * (1.f/65536.f) - 0.5f;
    // normalize init
    {
        float ss = r0*r0 + r1*r1;
#pragma unroll
        for (int d = 32; d > 0; d >>= 1) ss += __shfl_down(ss, d);
        if (lane == 0) red[wv] = ss;
        __syncthreads();
        if (i == 0){
            float t2 = 0.f;
#pragma unroll
            for (int k = 0; k < 8; ++k) t2 += red[k];
            sB = sqrtf(t2);
        }
        __syncthreads();
        float inv = 1.f / sB;
        V1r[i] = r0 * inv; V1i[i] = r1 * inv;
        __syncthreads();
    }
    float v0r = 0.f, v0i = 0.f;       // v_{j-1} only needed at own index
    float betaPrev = 0.f;
    int mEff = LM;
    for (int j = 0; j < LM; ++j){
        // w = A v1
        float wr = 0.f, wi = 0.f;
#pragma unroll
        for (int e = 0; e < RCAP; ++e){
            u32 en = enR[e]; float v = evR[e];
            int jj = en & 511;
            float xr = V1r[jj], xi = V1i[jj];
            bool ty = (en & 512u) != 0;
            wr = fmaf(v, ty ? -xi : xr, wr);
            wi = fmaf(v, ty ?  xr : xi, wi);
        }
        for (int e = RCAP; e < len; ++e){   // rare tail
            u32 en = er[e]; float v = ev[e];
            int jj = en & 511;
            float xr = V1r[jj], xi = V1i[jj];
            bool ty = (en & 512u) != 0;
            wr = fmaf(v, ty ? -xi : xr, wr);
            wi = fmaf(v, ty ?  xr : xi, wi);
        }
        // alpha = <v1, w> (real; A Hermitian)
        float pa = V1r[i]*wr + V1i[i]*wi;
#pragma unroll
        for (int d = 32; d > 0; d >>= 1) pa += __shfl_down(pa, d);
        if (lane == 0) red[wv] = pa;
        __syncthreads();
        if (i == 0){
            float t2 = 0.f;
#pragma unroll
            for (int k = 0; k < 8; ++k) t2 += red[k];
            sA = t2;
        }
        __syncthreads();
        float a = sA;
        wr -= a*V1r[i] + betaPrev*v0r;
        wi -= a*V1i[i] + betaPrev*v0i;
        float pb = wr*wr + wi*wi;
#pragma unroll
        for (int d = 32; d > 0; d >>= 1) pb += __shfl_down(pb, d);
        if (lane == 0) red[wv] = pb;
        __syncthreads();
        if (i == 0){
            float t2 = 0.f;
#pragma unroll
            for (int k = 0; k < 8; ++k) t2 += red[k];
            sB = sqrtf(t2);
            alph[j] = (double)a;
            bet[j+1] = (double)sB;
        }
        __syncthreads();
        float bta = sB;
        if (bta < 1e-6f){ mEff = j + 1; break; }   // uniform
        float inv = 1.f / bta;
        v0r = V1r[i]; v0i = V1i[i];                // own index only
        V1r[i] = wr * inv; V1i[i] = wi * inv;      // cross-reads were pre-barrier
        __syncthreads();
        betaPrev = bta;
    }
    if (i == 0){
        int m = mEff;
        bet[0] = 0.0;
        // Gershgorin bounds on T
        double lo = 1e300, hi = -1e300;
        for (int k = 0; k < m; ++k){
            double b0 = (k > 0)     ? fabs(bet[k])   : 0.0;
            double b1 = (k < m - 1) ? fabs(bet[k+1]) : 0.0;
            double c = alph[k];
            if (c - b0 - b1 < lo) lo = c - b0 - b1;
            if (c + b0 + b1 > hi) hi = c + b0 + b1;
        }
        for (int it = 0; it < 80; ++it){
            double mid = 0.5 * (lo + hi);
            int cnt = 0;
            double d = alph[0] - mid;
            if (d < 0) cnt++;
            for (int k = 1; k < m; ++k){
                if (d == 0.0) d = -1e-300;
                d = (alph[k] - mid) - bet[k]*bet[k] / d;
                if (d < 0) cnt++;
            }
            if (cnt >= m) hi = mid; else lo = mid;
        }
        float l1 = (float)hi;
        if (l1 < 0.f) l1 = 0.f;
        atomicMax((u32*)lam, __float_as_uint(l1));
    }
}

// ---------------- prep: xf = [nodes; 0] fp32 aug-node-major ----------------
__global__ void k_prep32(const float* __restrict__ nodes, float* __restrict__ xf){
    int row = blockIdx.x;                      // b*NAUG + i, 65536 blocks
    int t = threadIdx.x;
    int b = row >> 10, i = row & (NAUG - 1);
    float v = (i < NN) ? nodes[((size_t)b*NN + i)*DM + t] : 0.f;
    xf[(size_t)row*DM + t] = v;
}

// ---------------- SpMM: xt1 = (2/lam)*(lap @ x) - x, fp64 accum ----------------
__global__ __launch_bounds__(256)
void k_spmm(const u32* __restrict__ ents, const float* __restrict__ vals,
            const int* __restrict__ lens, const float* __restrict__ xf,
            const float* __restrict__ lam, float* __restrict__ xt1){
    int i = blockIdx.x;                        // 0..511
    int b = blockIdx.y;
    int t = threadIdx.x;
    int len = lens[b*NN + i];
    const u32*   er = ents + ((size_t)b*NN + i)*CAP;
    const float* ev = vals + ((size_t)b*NN + i)*CAP;
    const float* xb = xf + (size_t)b*NAUG*DM;
    double ar = 0.0, ai = 0.0;
    for (int e = 0; e < len; ++e){
        u32 en = er[e];
        double v = (double)ev[e];
        int j = en & 511;
        double xr = (double)xb[(size_t)j*DM + t];
        double xi = (double)xb[(size_t)(NN + j)*DM + t];
        if (en & 512u){ ar = fma(v, -xi, ar); ai = fma(v, xr, ai); }
        else          { ar = fma(v,  xr, ar); ai = fma(v, xi, ai); }
    }
    double alpha = 2.0 / (double)lam[0];
    size_t ro = ((size_t)b*NAUG + i)*DM + t;
    size_t io = ((size_t)b*NAUG + NN + i)*DM + t;
    xt1[ro] = (float)(alpha*ar - (double)xf[ro]);
    xt1[io] = (float)(alpha*ai - (double)xf[io]);
}

// ---------------- hybrid GEMM: s = x@w0 + xt1@w1 + bias ----------------
// fp32 fmaf within each 32-k block; block sums accumulated in fp64 (summation
// noise -> ~1e-8, below the fp32-storage noise floor; ~10% over pure fp32)
__global__ __launch_bounds__(256)
void k_gemm32(const float* __restrict__ xf, const float* __restrict__ xt1,
              const float* __restrict__ w0, const float* __restrict__ w1,
              const float* __restrict__ bias, float* __restrict__ sOut){
    __shared__ float As[32][68];
    __shared__ float Bs[32][68];
    int m0 = blockIdx.y * 64;                  // flat row over BATCH*NAUG
    int n0 = blockIdx.x * 64;
    int tid = threadIdx.x;
    int tx = tid & 15, ty = tid >> 4;
    double acc[4][4];
#pragma unroll
    for (int r = 0; r < 4; ++r)
#pragma unroll
        for (int c = 0; c < 4; ++c) acc[r][c] = 0.0;
    for (int ph = 0; ph < 2; ++ph){
        const float* A = ph ? xt1 : xf;
        const float* W = ph ? w1 : w0;
        for (int k0 = 0; k0 < DM; k0 += 32){
#pragma unroll
            for (int l = 0; l < 2; ++l){
                int fi = tid + l*256;          // 512 float4 slots each
                int m  = fi >> 3, c4 = fi & 7; // A: 64 rows x 8 f4
                float4 g = *(const float4*)(A + ((size_t)(m0 + m))*DM + k0 + c4*4);
                As[c4*4+0][m] = g.x; As[c4*4+1][m] = g.y;
                As[c4*4+2][m] = g.z; As[c4*4+3][m] = g.w;
                int kk = fi >> 4, n4 = fi & 15;// B: 32 k x 16 f4
                float4 hh = *(const float4*)(W + ((size_t)(k0 + kk))*DM + n0 + n4*4);
                *(float4*)&Bs[kk][n4*4] = hh;
            }
            __syncthreads();
            float facc[4][4];
#pragma unroll
            for (int r = 0; r < 4; ++r)
#pragma unroll
                for (int c = 0; c < 4; ++c) facc[r][c] = 0.f;
#pragma unroll
            for (int kk = 0; kk < 32; ++kk){
                float4 a4 = *(const float4*)&As[kk][ty*4];
                float4 b4 = *(const float4*)&Bs[kk][tx*4];
                facc[0][0] = fmaf(a4.x, b4.x, facc[0][0]);
                facc[0][1] = fmaf(a4.x, b4.y, facc[0][1]);
                facc[0][2] = fmaf(a4.x, b4.z, facc[0][2]);
                facc[0][3] = fmaf(a4.x, b4.w, facc[0][3]);
                facc[1][0] = fmaf(a4.y, b4.x, facc[1][0]);
                facc[1][1] = fmaf(a4.y, b4.y, facc[1][1]);
                facc[1][2] = fmaf(a4.y, b4.z, facc[1][2]);
                facc[1][3] = fmaf(a4.y, b4.w, facc[1][3]);
                facc[2][0] = fmaf(a4.z, b4.x, facc[2][0]);
                facc[2][1] = fmaf(a4.z, b4.y, facc[2][1]);
                facc[2][2] = fmaf(a4.z, b4.z, facc[2][2]);
                facc[2][3] = fmaf(a4.z, b4.w, facc[2][3]);
                facc[3][0] = fmaf(a4.w, b4.x, facc[3][0]);
                facc[3][1] = fmaf(a4.w, b4.y, facc[3][1]);
                facc[3][2] = fmaf(a4.w, b4.z, facc[3][2]);
                facc[3][3] = fmaf(a4.w, b4.w, facc[3][3]);
            }
#pragma unroll
            for (int r = 0; r < 4; ++r)
#pragma unroll
                for (int c = 0; c < 4; ++c) acc[r][c] += (double)facc[r][c];
            __syncthreads();
        }
    }
    float4 bi = *(const float4*)(bias + n0 + tx*4);
#pragma unroll
    for (int r = 0; r < 4; ++r){
        float4 o;
        o.x = (float)(acc[r][0] + (double)bi.x);
        o.y = (float)(acc[r][1] + (double)bi.y);
        o.z = (float)(acc[r][2] + (double)bi.z);
        o.w = (float)(acc[r][3] + (double)bi.w);
        *(float4*)&sOut[((size_t)(m0 + ty*4 + r))*DM + n0 + tx*4] = o;
    }
}

// ---------------- combine: crelu -> next-layer x (fp32) or final output ----------
__global__ void k_combine32(const float* __restrict__ sIn, float* __restrict__ xf,
                            float* __restrict__ out, int isFinal){
    int i = blockIdx.x;                        // 0..511
    int b = blockIdx.y;
    int t = threadIdx.x;
    size_t ro = ((size_t)b*NAUG + i)*DM + t;
    size_t io = ((size_t)b*NAUG + NN + i)*DM + t;
    float re = sIn[ro], im = sIn[io];
    if (!(re >= 0.f)){ re = 0.f; im = 0.f; }   // (v.real >= 0) * v
    if (isFinal){
        out[((size_t)b*NN + i)*(2*DM) + t]      = re;
        out[((size_t)b*NN + i)*(2*DM) + DM + t] = im;
    } else {
        xf[ro] = re; xf[io] = im;
    }
}

// ---------------- host launch ----------------
extern "C" void kernel_launch(void* const* d_in, const int* in_sizes, int n_in,
                              void* d_out, int out_size, void* d_ws, size_t ws_size,
                              hipStream_t stream){
    const float* nodes   = (const float*)d_in[0];
    const int*   senders = (const int*)  d_in[1];
    const int*   recvs   = (const int*)  d_in[2];
    const int*   n_node  = (const int*)  d_in[3];
    const float* w00     = (const float*)d_in[4];
    const float* b00     = (const float*)d_in[5];
    const float* w10     = (const float*)d_in[6];
    const float* w01     = (const float*)d_in[7];
    const float* b01     = (const float*)d_in[8];
    const float* w11     = (const float*)d_in[9];
    char* ws = (char*)d_ws;
    u64*   adj    = (u64*)  (ws + OFF_ADJ);
    u64*   adjT   = (u64*)  (ws + OFF_ADJT);
    float* lam    = (float*)(ws + OFF_LAM);
    float* degInv = (float*)(ws + OFF_DEGI);
    int*   lens   = (int*)  (ws + OFF_LENS);
    u32*   ents   = (u32*)  (ws + OFF_ENTS);
    float* vals   = (float*)(ws + OFF_VALS);
    float* xf     = (float*)(ws + OFF_XF);
    float* xt1    = (float*)(ws + OFF_XT1);
    float* sBuf   = (float*)(ws + OFF_S);
    float* out    = (float*)d_out;

    // zero adjacency bitmasks + lambda (everything else is fully overwritten)
    hipMemsetAsync(ws + OFF_ADJ, 0, 2*SZ_ADJ + 256, stream);

    k_scatter<<<dim3(BATCH*NEDGE/256), dim3(256), 0, stream>>>(senders, recvs, adj, adjT);
    k_deg    <<<dim3(BATCH*NN/256),    dim3(256), 0, stream>>>(adj, adjT, degInv);
    k_build  <<<dim3(BATCH*NN/4),      dim3(256), 0, stream>>>(adj, adjT, degInv, n_node,
                                                               ents, vals, lens);
    k_lanczos<<<dim3(BATCH),           dim3(NN),  0, stream>>>(ents, vals, lens, lam);
    k_prep32 <<<dim3(BATCH*NAUG),      dim3(256), 0, stream>>>(nodes, xf);

    for (int layer = 0; layer < 2; ++layer){
        const float* w0 = layer ? w01 : w00;
        const float* w1 = layer ? w11 : w10;
        const float* bias = layer ? b01 : b00;
        k_spmm   <<<dim3(NN, BATCH),   dim3(256), 0, stream>>>(ents, vals, lens, xf, lam, xt1);
        k_gemm32 <<<dim3(DM/64, BATCH*NAUG/64), dim3(256), 0, stream>>>(xf, xt1, w0, w1, bias, sBuf);
        k_combine32<<<dim3(NN, BATCH), dim3(256), 0, stream>>>(sBuf, xf, out, layer);
    }
}

// Round 5
// 3225.198 us; speedup vs baseline: 1.2559x; 1.2559x over previous
//
#include <hip/hip_runtime.h>
#include <stdint.h>

typedef unsigned long long u64;
typedef unsigned int u32;
typedef unsigned short u16;

#define BATCH 64
#define NN    512
#define NAUG  1024
#define DM    256
#define NEDGE 4096
#define CAP   64
#define LM    192      // Lanczos steps

// ---------------- workspace layout (bytes) ----------------
#define OFF_ADJ   ((size_t)0)
#define SZ_ADJ    ((size_t)BATCH*NN*8*8)                 // 2 MiB bitmask
#define OFF_ADJT  (OFF_ADJ + SZ_ADJ)
#define OFF_LAM   (OFF_ADJT + SZ_ADJ)                    // 4B lambda
#define OFF_LMX   (OFF_LAM + 64)                         // int lmax[64]
#define OFF_PKT   (OFF_LAM + 1024)
#define SZ_PKT    ((size_t)BATCH*CAP*NN*16)              // 33.5 MB transposed packed lap
#define OFF_DEGI  (OFF_PKT + SZ_PKT)
#define OFF_LENS  (OFF_DEGI + (size_t)BATCH*NN*4)
#define OFF_ENTS  (OFF_LENS + (size_t)BATCH*NN*4)
#define OFF_VALS  (OFF_ENTS + (size_t)BATCH*NN*CAP*4)
#define OFF_XF    (OFF_VALS + (size_t)BATCH*NN*CAP*4)    // x fp32 [b,1024,256]
#define OFF_XT1   (OFF_XF  + (size_t)BATCH*NAUG*DM*4)    // t1@x fp32
#define OFF_S     (OFF_XT1 + (size_t)BATCH*NAUG*DM*4)    // pre-relu sums fp32

// ---------------- adjacency scatter (bitmask) ----------------
__global__ void k_scatter(const int* __restrict__ senders, const int* __restrict__ receivers,
                          u64* __restrict__ adj, u64* __restrict__ adjT){
    int idx = blockIdx.x * 256 + threadIdx.x;          // BATCH*NEDGE threads
    int b = idx >> 12;
    int s = senders[idx];
    int r = receivers[idx];
    if (s >= 0){
        atomicOr(&adj [((size_t)b*NN + s)*8 + (r >> 6)], 1ull << (r & 63));
        atomicOr(&adjT[((size_t)b*NN + r)*8 + (s >> 6)], 1ull << (s & 63));
    }
}

// ---------------- degree (exact double 1/sqrt) ----------------
__global__ void k_deg(const u64* __restrict__ adj, const u64* __restrict__ adjT,
                      float* __restrict__ degInv){
    int idx = blockIdx.x * 256 + threadIdx.x;          // BATCH*NN threads
    const u64* a = adj  + (size_t)idx * 8;
    const u64* t = adjT + (size_t)idx * 8;
    int deg = 0;
#pragma unroll
    for (int w = 0; w < 8; ++w) deg += __popcll(a[w] | t[w]);
    degInv[idx] = (float)(1.0 / sqrt((double)(deg < 1 ? 1 : deg)));
}

// ---------------- build CSR + transposed packed stream (one wave per row) ----------
// CSR entry (for k_spmm): bits[8:0]=col j, bit9=type (0 real, 1 imag), val fp32.
// pkT entry (for k_lanczos): uint4 {j*8 (byte off into float2 x[]), f32 gr, f32 gi, 0}
// at [b][p][i] (entry-major, zero-padded by host memset).
__global__ __launch_bounds__(256)
void k_build(const u64* __restrict__ adj, const u64* __restrict__ adjT,
             const float* __restrict__ degInv, const int* __restrict__ n_node,
             u32* __restrict__ ents, float* __restrict__ vals, int* __restrict__ lens,
             uint4* __restrict__ pkT, int* __restrict__ lmax){
    int gw   = (blockIdx.x * 256 + threadIdx.x) >> 6;  // global wave = row id
    int lane = threadIdx.x & 63;
    int b = gw >> 9;
    int i = gw & (NN - 1);
    const u64* arow = adj  + ((size_t)b*NN + i)*8;
    const u64* trow = adjT + ((size_t)b*NN + i)*8;
    int wsel = lane >> 3, sh = (lane & 7) * 8;
    u32 ba = (u32)((arow[wsel] >> sh) & 0xFFull);
    u32 bt = (u32)((trow[wsel] >> sh) & 0xFFull);
    int nn_b = n_node[b];
    bool mi  = i < nn_b;
    float di = degInv[b*NN + i];
    int j0 = lane * 8;

    float vr_[8], vi_[8];
    int cnt = 0;
#pragma unroll
    for (int jj = 0; jj < 8; ++jj){
        int j = j0 + jj;
        int a = (ba >> jj) & 1, t = (bt >> jj) & 1;
        bool mm = mi && (j < nn_b);
        float c = di * degInv[b*NN + j];
        float vr = 0.f, vi = 0.f;
        if (j == i){
            if (mm) vr = 1.0f - (a ? c : 0.0f);        // diag: mask*(1 - selfloop*c)
        } else if (mm && ((a | t) != 0)){
            if (a & t)      vr = -c;                   // lap = -c
            else if (a)     vi = -c;                   // lap = -i*c
            else            vi =  c;                   // lap = +i*c
        }
        vr_[jj] = vr; vi_[jj] = vi;
        cnt += (vr != 0.f || vi != 0.f) ? 1 : 0;
    }
    // wave-wide exclusive scan of cnt
    int off = cnt;
#pragma unroll
    for (int d = 1; d < 64; d <<= 1){
        int nb = __shfl_up(off, d);
        if (lane >= d) off += nb;
    }
    int excl = off - cnt;
    int tot  = __shfl(off, 63);
    int p = excl;
    u32*   erow = ents + ((size_t)b*NN + i)*CAP;
    float* vrow = vals + ((size_t)b*NN + i)*CAP;
#pragma unroll
    for (int jj = 0; jj < 8; ++jj){
        float vr = vr_[jj], vi = vi_[jj];
        if (vr != 0.f || vi != 0.f){
            if (p < CAP){
                int ty = (vi != 0.f) ? 1 : 0;
                int j = j0 + jj;
                erow[p] = (u32)j | ((u32)ty << 9);
                vrow[p] = ty ? vi : vr;
                pkT[((size_t)b*CAP + p)*NN + i] =
                    make_uint4((u32)(j << 3), __float_as_uint(vr), __float_as_uint(vi), 0u);
            }
            p++;
        }
    }
    if (lane == 63){
        int tc = tot > CAP ? CAP : tot;
        lens[b*NN + i] = tc;
        atomicMax(&lmax[b], tc);
    }
}

// ---------------- Lanczos: ONE WAVE per graph, zero barriers ----------------
// Lane l owns rows {l+64r}; x lives in LDS (float2), own components mirrored in
// regs. SpMV streams the transposed zero-padded pkT: per entry-step e, 8
// independent coalesced dwordx4 loads (double-buffered) + 8 LDS b64 + 32 fma —
// uniform trip count Emax, no divergence, no barrier (wave-lockstep LDS).
// All reductions are __shfl_xor butterflies (bitwise-identical on all lanes).
// lam_max(T) via 64-midpoint parallel Sturm bisection (65x narrowing/sweep).
__global__ __launch_bounds__(64)
void k_lanczos(const uint4* __restrict__ pkT, const int* __restrict__ lmax,
               float* __restrict__ lam){
    int b = blockIdx.x, l = threadIdx.x;
    __shared__ float2 X[NN];
    __shared__ float alphS[LM], betS[LM];
    int Emax = lmax[b];
    const uint4* base = pkT + (size_t)b*CAP*NN;
    float xr[8], xi[8];
    float ss = 0.f;
#pragma unroll
    for (int r = 0; r < 8; ++r){
        u32 h = (u32)(l + 64*r) * 2654435761u + 0x9E3779B9u;
        h ^= h >> 16; h *= 0x85EBCA6Bu; h ^= h >> 13;
        xr[r] = (float)(h & 0xFFFF) * (1.f/65536.f) - 0.5f;
        h = h * 1664525u + 1013904223u;
        xi[r] = (float)(h & 0xFFFF) * (1.f/65536.f) - 0.5f;
        ss += xr[r]*xr[r] + xi[r]*xi[r];
    }
#pragma unroll
    for (int d = 1; d < 64; d <<= 1) ss += __shfl_xor(ss, d);
    float inv0 = 1.f / sqrtf(ss);
#pragma unroll
    for (int r = 0; r < 8; ++r){
        xr[r] *= inv0; xi[r] *= inv0;
        X[l + 64*r] = make_float2(xr[r], xi[r]);
    }
    float v0r[8], v0i[8];
#pragma unroll
    for (int r = 0; r < 8; ++r){ v0r[r] = 0.f; v0i[r] = 0.f; }
    float betaPrev = 0.f;
    int mEff = LM;
    for (int j = 0; j < LM; ++j){
        float wr[8], wi[8];
#pragma unroll
        for (int r = 0; r < 8; ++r){ wr[r] = 0.f; wi[r] = 0.f; }
        uint4 q[8], nq[8];
        if (Emax > 0){
#pragma unroll
            for (int r = 0; r < 8; ++r) q[r] = base[(size_t)(64*r + l)];
        }
        for (int e = 0; e < Emax; ++e){
            if (e + 1 < Emax){
#pragma unroll
                for (int r = 0; r < 8; ++r)
                    nq[r] = base[(size_t)(e+1)*NN + 64*r + l];
            }
#pragma unroll
            for (int r = 0; r < 8; ++r){
                float2 xv = *(const float2*)((const char*)X + q[r].x);
                float gr = __uint_as_float(q[r].y);
                float gi = __uint_as_float(q[r].z);
                wr[r] = fmaf(gr, xv.x, fmaf(-gi, xv.y, wr[r]));
                wi[r] = fmaf(gr, xv.y, fmaf( gi, xv.x, wi[r]));
            }
#pragma unroll
            for (int r = 0; r < 8; ++r) q[r] = nq[r];
        }
        // alpha = Re<v1, w>
        float pa = 0.f;
#pragma unroll
        for (int r = 0; r < 8; ++r) pa += xr[r]*wr[r] + xi[r]*wi[r];
#pragma unroll
        for (int d = 1; d < 64; d <<= 1) pa += __shfl_xor(pa, d);
        // w -= alpha*v1 + betaPrev*v0 ; beta = ||w||
        float pb = 0.f;
#pragma unroll
        for (int r = 0; r < 8; ++r){
            wr[r] -= pa*xr[r] + betaPrev*v0r[r];
            wi[r] -= pa*xi[r] + betaPrev*v0i[r];
            pb += wr[r]*wr[r] + wi[r]*wi[r];
        }
#pragma unroll
        for (int d = 1; d < 64; d <<= 1) pb += __shfl_xor(pb, d);
        float bta = sqrtf(pb);
        if (l == 0){ alphS[j] = pa; betS[j] = bta; }
        if (bta < 1e-7f){ mEff = j + 1; break; }       // uniform (pb identical/lane)
        float binv = 1.f / bta;
#pragma unroll
        for (int r = 0; r < 8; ++r){
            v0r[r] = xr[r]; v0i[r] = xi[r];
            xr[r] = wr[r] * binv; xi[r] = wi[r] * binv;
            X[l + 64*r] = make_float2(xr[r], xi[r]);
        }
        betaPrev = bta;
    }
    // parallel-midpoint Sturm bisection: lane l tests mid_l; ballot brackets.
    int m = mEff;
    double lo = -0.5, hi = 2.5;                        // lap spectrum in [0,2]
    for (int sweep = 0; sweep < 5; ++sweep){
        double w = (hi - lo) * (1.0/65.0);
        double mid = lo + w * (double)(l + 1);
        int cnt = 0;
        double d = (double)alphS[0] - mid;
        if (d < 0.0) cnt++;
        for (int k = 1; k < m; ++k){
            if (d == 0.0) d = -1e-300;
            double bk = (double)betS[k-1];
            d = ((double)alphS[k] - mid) - bk*bk/d;
            if (d < 0.0) cnt++;
        }
        u64 mask = __ballot(cnt >= m);                 // mid above lam_max
        if (mask == 0ull){
            lo = lo + w * 64.0;
        } else {
            int L = __ffsll(mask) - 1;
            hi = lo + w * (double)(L + 1);
            lo = lo + w * (double)L;
        }
    }
    if (l == 0){
        float l1 = (float)hi;
        if (l1 < 0.f) l1 = 0.f;
        atomicMax((u32*)lam, __float_as_uint(l1));
    }
}

// ---------------- prep: xf = [nodes; 0] fp32 aug-node-major ----------------
__global__ void k_prep32(const float* __restrict__ nodes, float* __restrict__ xf){
    int row = blockIdx.x;                      // b*NAUG + i, 65536 blocks
    int t = threadIdx.x;
    int b = row >> 10, i = row & (NAUG - 1);
    float v = (i < NN) ? nodes[((size_t)b*NN + i)*DM + t] : 0.f;
    xf[(size_t)row*DM + t] = v;
}

// ---------------- SpMM: xt1 = (2/lam)*(lap @ x) - x, fp64 accum ----------------
__global__ __launch_bounds__(256)
void k_spmm(const u32* __restrict__ ents, const float* __restrict__ vals,
            const int* __restrict__ lens, const float* __restrict__ xf,
            const float* __restrict__ lam, float* __restrict__ xt1){
    int i = blockIdx.x;                        // 0..511
    int b = blockIdx.y;
    int t = threadIdx.x;
    int len = lens[b*NN + i];
    const u32*   er = ents + ((size_t)b*NN + i)*CAP;
    const float* ev = vals + ((size_t)b*NN + i)*CAP;
    const float* xb = xf + (size_t)b*NAUG*DM;
    double ar = 0.0, ai = 0.0;
    for (int e = 0; e < len; ++e){
        u32 en = er[e];
        double v = (double)ev[e];
        int j = en & 511;
        double xr = (double)xb[(size_t)j*DM + t];
        double xi = (double)xb[(size_t)(NN + j)*DM + t];
        if (en & 512u){ ar = fma(v, -xi, ar); ai = fma(v, xr, ai); }
        else          { ar = fma(v,  xr, ar); ai = fma(v, xi, ai); }
    }
    double alpha = 2.0 / (double)lam[0];
    size_t ro = ((size_t)b*NAUG + i)*DM + t;
    size_t io = ((size_t)b*NAUG + NN + i)*DM + t;
    xt1[ro] = (float)(alpha*ar - (double)xf[ro]);
    xt1[io] = (float)(alpha*ai - (double)xf[io]);
}

// ---------------- hybrid GEMM: s = x@w0 + xt1@w1 + bias ----------------
// fp32 fmaf within each 32-k block; block sums accumulated in fp64
__global__ __launch_bounds__(256)
void k_gemm32(const float* __restrict__ xf, const float* __restrict__ xt1,
              const float* __restrict__ w0, const float* __restrict__ w1,
              const float* __restrict__ bias, float* __restrict__ sOut){
    __shared__ float As[32][68];
    __shared__ float Bs[32][68];
    int m0 = blockIdx.y * 64;                  // flat row over BATCH*NAUG
    int n0 = blockIdx.x * 64;
    int tid = threadIdx.x;
    int tx = tid & 15, ty = tid >> 4;
    double acc[4][4];
#pragma unroll
    for (int r = 0; r < 4; ++r)
#pragma unroll
        for (int c = 0; c < 4; ++c) acc[r][c] = 0.0;
    for (int ph = 0; ph < 2; ++ph){
        const float* A = ph ? xt1 : xf;
        const float* W = ph ? w1 : w0;
        for (int k0 = 0; k0 < DM; k0 += 32){
#pragma unroll
            for (int l = 0; l < 2; ++l){
                int fi = tid + l*256;          // 512 float4 slots each
                int m  = fi >> 3, c4 = fi & 7; // A: 64 rows x 8 f4
                float4 g = *(const float4*)(A + ((size_t)(m0 + m))*DM + k0 + c4*4);
                As[c4*4+0][m] = g.x; As[c4*4+1][m] = g.y;
                As[c4*4+2][m] = g.z; As[c4*4+3][m] = g.w;
                int kk = fi >> 4, n4 = fi & 15;// B: 32 k x 16 f4
                float4 hh = *(const float4*)(W + ((size_t)(k0 + kk))*DM + n0 + n4*4);
                *(float4*)&Bs[kk][n4*4] = hh;
            }
            __syncthreads();
            float facc[4][4];
#pragma unroll
            for (int r = 0; r < 4; ++r)
#pragma unroll
                for (int c = 0; c < 4; ++c) facc[r][c] = 0.f;
#pragma unroll
            for (int kk = 0; kk < 32; ++kk){
                float4 a4 = *(const float4*)&As[kk][ty*4];
                float4 b4 = *(const float4*)&Bs[kk][tx*4];
                facc[0][0] = fmaf(a4.x, b4.x, facc[0][0]);
                facc[0][1] = fmaf(a4.x, b4.y, facc[0][1]);
                facc[0][2] = fmaf(a4.x, b4.z, facc[0][2]);
                facc[0][3] = fmaf(a4.x, b4.w, facc[0][3]);
                facc[1][0] = fmaf(a4.y, b4.x, facc[1][0]);
                facc[1][1] = fmaf(a4.y, b4.y, facc[1][1]);
                facc[1][2] = fmaf(a4.y, b4.z, facc[1][2]);
                facc[1][3] = fmaf(a4.y, b4.w, facc[1][3]);
                facc[2][0] = fmaf(a4.z, b4.x, facc[2][0]);
                facc[2][1] = fmaf(a4.z, b4.y, facc[2][1]);
                facc[2][2] = fmaf(a4.z, b4.z, facc[2][2]);
                facc[2][3] = fmaf(a4.z, b4.w, facc[2][3]);
                facc[3][0] = fmaf(a4.w, b4.x, facc[3][0]);
                facc[3][1] = fmaf(a4.w, b4.y, facc[3][1]);
                facc[3][2] = fmaf(a4.w, b4.z, facc[3][2]);
                facc[3][3] = fmaf(a4.w, b4.w, facc[3][3]);
            }
#pragma unroll
            for (int r = 0; r < 4; ++r)
#pragma unroll
                for (int c = 0; c < 4; ++c) acc[r][c] += (double)facc[r][c];
            __syncthreads();
        }
    }
    float4 bi = *(const float4*)(bias + n0 + tx*4);
#pragma unroll
    for (int r = 0; r < 4; ++r){
        float4 o;
        o.x = (float)(acc[r][0] + (double)bi.x);
        o.y = (float)(acc[r][1] + (double)bi.y);
        o.z = (float)(acc[r][2] + (double)bi.z);
        o.w = (float)(acc[r][3] + (double)bi.w);
        *(float4*)&sOut[((size_t)(m0 + ty*4 + r))*DM + n0 + tx*4] = o;
    }
}

// ---------------- combine: crelu -> next-layer x (fp32) or final output ----------
__global__ void k_combine32(const float* __restrict__ sIn, float* __restrict__ xf,
                            float* __restrict__ out, int isFinal){
    int i = blockIdx.x;                        // 0..511
    int b = blockIdx.y;
    int t = threadIdx.x;
    size_t ro = ((size_t)b*NAUG + i)*DM + t;
    size_t io = ((size_t)b*NAUG + NN + i)*DM + t;
    float re = sIn[ro], im = sIn[io];
    if (!(re >= 0.f)){ re = 0.f; im = 0.f; }   // (v.real >= 0) * v
    if (isFinal){
        out[((size_t)b*NN + i)*(2*DM) + t]      = re;
        out[((size_t)b*NN + i)*(2*DM) + DM + t] = im;
    } else {
        xf[ro] = re; xf[io] = im;
    }
}

// ---------------- host launch ----------------
extern "C" void kernel_launch(void* const* d_in, const int* in_sizes, int n_in,
                              void* d_out, int out_size, void* d_ws, size_t ws_size,
                              hipStream_t stream){
    const float* nodes   = (const float*)d_in[0];
    const int*   senders = (const int*)  d_in[1];
    const int*   recvs   = (const int*)  d_in[2];
    const int*   n_node  = (const int*)  d_in[3];
    const float* w00     = (const float*)d_in[4];
    const float* b00     = (const float*)d_in[5];
    const float* w10     = (const float*)d_in[6];
    const float* w01     = (const float*)d_in[7];
    const float* b01     = (const float*)d_in[8];
    const float* w11     = (const float*)d_in[9];
    char* ws = (char*)d_ws;
    u64*   adj    = (u64*)  (ws + OFF_ADJ);
    u64*   adjT   = (u64*)  (ws + OFF_ADJT);
    float* lam    = (float*)(ws + OFF_LAM);
    int*   lmax   = (int*)  (ws + OFF_LMX);
    uint4* pkT    = (uint4*)(ws + OFF_PKT);
    float* degInv = (float*)(ws + OFF_DEGI);
    int*   lens   = (int*)  (ws + OFF_LENS);
    u32*   ents   = (u32*)  (ws + OFF_ENTS);
    float* vals   = (float*)(ws + OFF_VALS);
    float* xf     = (float*)(ws + OFF_XF);
    float* xt1    = (float*)(ws + OFF_XT1);
    float* sBuf   = (float*)(ws + OFF_S);
    float* out    = (float*)d_out;

    // zero adj bitmasks + lambda/lmax + pkT (zero-padding of the entry stream)
    hipMemsetAsync(ws + OFF_ADJ, 0, OFF_PKT + SZ_PKT, stream);

    k_scatter<<<dim3(BATCH*NEDGE/256), dim3(256), 0, stream>>>(senders, recvs, adj, adjT);
    k_deg    <<<dim3(BATCH*NN/256),    dim3(256), 0, stream>>>(adj, adjT, degInv);
    k_build  <<<dim3(BATCH*NN/4),      dim3(256), 0, stream>>>(adj, adjT, degInv, n_node,
                                                               ents, vals, lens, pkT, lmax);
    k_lanczos<<<dim3(BATCH),           dim3(64),  0, stream>>>(pkT, lmax, lam);
    k_prep32 <<<dim3(BATCH*NAUG),      dim3(256), 0, stream>>>(nodes, xf);

    for (int layer = 0; layer < 2; ++layer){
        const float* w0 = layer ? w01 : w00;
        const float* w1 = layer ? w11 : w10;
        const float* bias = layer ? b01 : b00;
        k_spmm   <<<dim3(NN, BATCH),   dim3(256), 0, stream>>>(ents, vals, lens, xf, lam, xt1);
        k_gemm32 <<<dim3(DM/64, BATCH*NAUG/64), dim3(256), 0, stream>>>(xf, xt1, w0, w1, bias, sBuf);
        k_combine32<<<dim3(NN, BATCH), dim3(256), 0, stream>>>(sBuf, xf, out, layer);
    }
}

// Round 7
// 2243.639 us; speedup vs baseline: 1.8053x; 1.4375x over previous
//
#include <hip/hip_runtime.h>
#include <stdint.h>

typedef unsigned long long u64;
typedef unsigned int u32;
typedef unsigned short u16;

#define BATCH 64
#define NN    512
#define NAUG  1024
#define DM    256
#define NEDGE 4096
#define CAP   64
#define PK2   32       // packed entry-pair slots = CAP/2
#define LM    192      // Lanczos steps

// ---------------- workspace layout (bytes) ----------------
#define OFF_ADJ   ((size_t)0)
#define SZ_ADJ    ((size_t)BATCH*NN*8*8)                 // 2 MiB bitmask
#define OFF_ADJT  (OFF_ADJ + SZ_ADJ)
#define OFF_LAM   (OFF_ADJT + SZ_ADJ)                    // 4B lambda
#define OFF_LMX   (OFF_LAM + 64)                         // int lmax[64]
#define OFF_PK2   (OFF_LAM + 1024)
#define SZ_PK2    ((size_t)BATCH*PK2*NN*16)              // 16.8 MB packed-pair lap stream
#define OFF_DEGI  (OFF_PK2 + SZ_PK2)
#define OFF_LENS  (OFF_DEGI + (size_t)BATCH*NN*4)
#define OFF_ENTS  (OFF_LENS + (size_t)BATCH*NN*4)
#define OFF_VALS  (OFF_ENTS + (size_t)BATCH*NN*CAP*4)
#define OFF_XF    (OFF_VALS + (size_t)BATCH*NN*CAP*4)    // x fp32 [b,1024,256]
#define OFF_XT1   (OFF_XF  + (size_t)BATCH*NAUG*DM*4)    // t1@x fp32
#define OFF_S     (OFF_XT1 + (size_t)BATCH*NAUG*DM*4)    // pre-relu sums fp32

// ---------------- adjacency scatter (bitmask) ----------------
__global__ void k_scatter(const int* __restrict__ senders, const int* __restrict__ receivers,
                          u64* __restrict__ adj, u64* __restrict__ adjT){
    int idx = blockIdx.x * 256 + threadIdx.x;          // BATCH*NEDGE threads
    int b = idx >> 12;
    int s = senders[idx];
    int r = receivers[idx];
    if (s >= 0){
        atomicOr(&adj [((size_t)b*NN + s)*8 + (r >> 6)], 1ull << (r & 63));
        atomicOr(&adjT[((size_t)b*NN + r)*8 + (s >> 6)], 1ull << (s & 63));
    }
}

// ---------------- degree (exact double 1/sqrt) ----------------
__global__ void k_deg(const u64* __restrict__ adj, const u64* __restrict__ adjT,
                      float* __restrict__ degInv){
    int idx = blockIdx.x * 256 + threadIdx.x;          // BATCH*NN threads
    const u64* a = adj  + (size_t)idx * 8;
    const u64* t = adjT + (size_t)idx * 8;
    int deg = 0;
#pragma unroll
    for (int w = 0; w < 8; ++w) deg += __popcll(a[w] | t[w]);
    degInv[idx] = (float)(1.0 / sqrt((double)(deg < 1 ? 1 : deg)));
}

// ---------------- build CSR + packed-pair stream (one wave per row) ----------
// CSR entry (k_spmm): bits[8:0]=col j, bit9=type; val fp32.
// pk2 entry (k_lanczos): uint2 {byteoff = j*8 + ty*4096, f32 val} — two entries
// packed per uint4 slot at [b][p>>1][i], half selected by p&1. Zero-padded by
// host memset (off=0,val=0 -> reads X[0]*0, harmless).
__global__ __launch_bounds__(256)
void k_build(const u64* __restrict__ adj, const u64* __restrict__ adjT,
             const float* __restrict__ degInv, const int* __restrict__ n_node,
             u32* __restrict__ ents, float* __restrict__ vals, int* __restrict__ lens,
             uint2* __restrict__ pk2, int* __restrict__ lmax){
    int gw   = (blockIdx.x * 256 + threadIdx.x) >> 6;  // global wave = row id
    int lane = threadIdx.x & 63;
    int b = gw >> 9;
    int i = gw & (NN - 1);
    const u64* arow = adj  + ((size_t)b*NN + i)*8;
    const u64* trow = adjT + ((size_t)b*NN + i)*8;
    int wsel = lane >> 3, sh = (lane & 7) * 8;
    u32 ba = (u32)((arow[wsel] >> sh) & 0xFFull);
    u32 bt = (u32)((trow[wsel] >> sh) & 0xFFull);
    int nn_b = n_node[b];
    bool mi  = i < nn_b;
    float di = degInv[b*NN + i];
    int j0 = lane * 8;

    float vr_[8], vi_[8];
    int cnt = 0;
#pragma unroll
    for (int jj = 0; jj < 8; ++jj){
        int j = j0 + jj;
        int a = (ba >> jj) & 1, t = (bt >> jj) & 1;
        bool mm = mi && (j < nn_b);
        float c = di * degInv[b*NN + j];
        float vr = 0.f, vi = 0.f;
        if (j == i){
            if (mm) vr = 1.0f - (a ? c : 0.0f);        // diag: mask*(1 - selfloop*c)
        } else if (mm && ((a | t) != 0)){
            if (a & t)      vr = -c;                   // lap = -c
            else if (a)     vi = -c;                   // lap = -i*c
            else            vi =  c;                   // lap = +i*c
        }
        vr_[jj] = vr; vi_[jj] = vi;
        cnt += (vr != 0.f || vi != 0.f) ? 1 : 0;
    }
    // wave-wide exclusive scan of cnt
    int off = cnt;
#pragma unroll
    for (int d = 1; d < 64; d <<= 1){
        int nb = __shfl_up(off, d);
        if (lane >= d) off += nb;
    }
    int excl = off - cnt;
    int tot  = __shfl(off, 63);
    int p = excl;
    u32*   erow = ents + ((size_t)b*NN + i)*CAP;
    float* vrow = vals + ((size_t)b*NN + i)*CAP;
#pragma unroll
    for (int jj = 0; jj < 8; ++jj){
        float vr = vr_[jj], vi = vi_[jj];
        if (vr != 0.f || vi != 0.f){
            if (p < CAP){
                int ty = (vi != 0.f) ? 1 : 0;
                int j = j0 + jj;
                float v = ty ? vi : vr;
                erow[p] = (u32)j | ((u32)ty << 9);
                vrow[p] = v;
                size_t slot = ((size_t)b*PK2 + (p >> 1))*NN + i;
                pk2[slot*2 + (p & 1)] =
                    make_uint2((u32)((j << 3) + (ty << 12)), __float_as_uint(v));
            }
            p++;
        }
    }
    if (lane == 63){
        int tc = tot > CAP ? CAP : tot;
        lens[b*NN + i] = tc;
        atomicMax(&lmax[b], tc);
    }
}

// ---------------- Lanczos: ONE WAVE per graph, zero barriers ----------------
// Lane l owns rows {l+64r}. XY LDS: X[j]=(xr,xi) at byte 8j, Y[j]=(-xi,xr) at
// 4096+8j — entry's type folded into its byte offset (ds_read_b64 + 2 fma,
// no cndmask). 2 entries per 16B stream load, 1-deep prefetch.
// beta = ||w - a*v - b*v0|| computed EXPLICITLY (2nd butterfly): the fused
// formula beta^2 = |w|^2 - a^2 - b^2 (R6) is numerically unstable — when the
// true residual is small the fp32 cancellation noise (~5e-7 on |w|^2 ~ 4)
// gives beta with O(1) relative error, de-normalizing v_{j+1} and inflating
// later T rows multiplicatively (Paige: stability requires norm-computed beta).
__global__ __launch_bounds__(64)
void k_lanczos(const uint4* __restrict__ pk2, const int* __restrict__ lmax,
               float* __restrict__ lam){
    int b = blockIdx.x, l = threadIdx.x;
    __shared__ float2 XY[2*NN];                        // X then Y
    __shared__ float alphS[LM], betS[LM];
    int Emax = lmax[b];
    int ES = (Emax + 1) >> 1;
    if (ES > PK2) ES = PK2;
    const uint4* base = pk2 + (size_t)b*PK2*NN;
    float xr[8], xi[8];
    float ss = 0.f;
#pragma unroll
    for (int r = 0; r < 8; ++r){
        u32 h = (u32)(l + 64*r) * 2654435761u + 0x9E3779B9u;
        h ^= h >> 16; h *= 0x85EBCA6Bu; h ^= h >> 13;
        xr[r] = (float)(h & 0xFFFF) * (1.f/65536.f) - 0.5f;
        h = h * 1664525u + 1013904223u;
        xi[r] = (float)(h & 0xFFFF) * (1.f/65536.f) - 0.5f;
        ss += xr[r]*xr[r] + xi[r]*xi[r];
    }
#pragma unroll
    for (int d = 1; d < 64; d <<= 1) ss += __shfl_xor(ss, d);
    float inv0 = 1.f / sqrtf(ss);
#pragma unroll
    for (int r = 0; r < 8; ++r){
        xr[r] *= inv0; xi[r] *= inv0;
        XY[l + 64*r]      = make_float2(xr[r], xi[r]);
        XY[NN + l + 64*r] = make_float2(-xi[r], xr[r]);
    }
    float v0r[8], v0i[8];
#pragma unroll
    for (int r = 0; r < 8; ++r){ v0r[r] = 0.f; v0i[r] = 0.f; }
    float betaPrev = 0.f;
    int mEff = LM;
    for (int j = 0; j < LM; ++j){
        float wr[8], wi[8];
#pragma unroll
        for (int r = 0; r < 8; ++r){ wr[r] = 0.f; wi[r] = 0.f; }
        uint4 q[8], nq[8];
        if (ES > 0){
#pragma unroll
            for (int r = 0; r < 8; ++r) q[r] = base[(size_t)(64*r + l)];
        }
        for (int e = 0; e < ES; ++e){
            if (e + 1 < ES){
#pragma unroll
                for (int r = 0; r < 8; ++r)
                    nq[r] = base[(size_t)(e+1)*NN + 64*r + l];
            }
#pragma unroll
            for (int r = 0; r < 8; ++r){
                float2 u0 = *(const float2*)((const char*)XY + q[r].x);
                float g0 = __uint_as_float(q[r].y);
                wr[r] = fmaf(g0, u0.x, wr[r]);
                wi[r] = fmaf(g0, u0.y, wi[r]);
                float2 u1 = *(const float2*)((const char*)XY + q[r].z);
                float g1 = __uint_as_float(q[r].w);
                wr[r] = fmaf(g1, u1.x, wr[r]);
                wi[r] = fmaf(g1, u1.y, wi[r]);
            }
#pragma unroll
            for (int r = 0; r < 8; ++r) q[r] = nq[r];
        }
        // alpha = Re<v1, w>
        float pa = 0.f;
#pragma unroll
        for (int r = 0; r < 8; ++r) pa += xr[r]*wr[r] + xi[r]*wi[r];
#pragma unroll
        for (int d = 1; d < 64; d <<= 1) pa += __shfl_xor(pa, d);
        // w -= alpha*v1 + betaPrev*v0 ; beta = ||w|| (explicit, stable)
        float pb = 0.f;
#pragma unroll
        for (int r = 0; r < 8; ++r){
            wr[r] -= pa*xr[r] + betaPrev*v0r[r];
            wi[r] -= pa*xi[r] + betaPrev*v0i[r];
            pb += wr[r]*wr[r] + wi[r]*wi[r];
        }
#pragma unroll
        for (int d = 1; d < 64; d <<= 1) pb += __shfl_xor(pb, d);
        float bta = sqrtf(pb);
        if (l == 0){ alphS[j] = pa; betS[j] = bta; }
        if (bta < 1e-7f){ mEff = j + 1; break; }       // breakdown: invariant subspace
        float binv = 1.f / bta;
#pragma unroll
        for (int r = 0; r < 8; ++r){
            float nr = wr[r] * binv;
            float ni = wi[r] * binv;
            v0r[r] = xr[r]; v0i[r] = xi[r];
            xr[r] = nr; xi[r] = ni;
            XY[l + 64*r]      = make_float2(nr, ni);
            XY[NN + l + 64*r] = make_float2(-ni, nr);
        }
        betaPrev = bta;
    }
    // parallel-midpoint Sturm bisection: lane l tests mid_l; ballot brackets.
    int m = mEff;
    double lo = -0.5, hi = 2.5;                        // lap spectrum in [0,2]
    for (int sweep = 0; sweep < 5; ++sweep){
        double w = (hi - lo) * (1.0/65.0);
        double mid = lo + w * (double)(l + 1);
        int cnt = 0;
        double d = (double)alphS[0] - mid;
        if (d < 0.0) cnt++;
        for (int k = 1; k < m; ++k){
            if (d == 0.0) d = -1e-300;
            double bk = (double)betS[k-1];
            d = ((double)alphS[k] - mid) - bk*bk/d;
            if (d < 0.0) cnt++;
        }
        u64 mask = __ballot(cnt >= m);                 // mid above lam_max
        if (mask == 0ull){
            lo = lo + w * 64.0;
        } else {
            int L = __ffsll(mask) - 1;
            hi = lo + w * (double)(L + 1);
            lo = lo + w * (double)L;
        }
    }
    if (l == 0){
        float l1 = (float)hi;
        if (l1 < 0.f) l1 = 0.f;
        if (l1 > 2.0f) l1 = 2.0f;                      // normalized-lap bound
        atomicMax((u32*)lam, __float_as_uint(l1));
    }
}

// ---------------- prep: xf = [nodes; 0] fp32 aug-node-major ----------------
__global__ void k_prep32(const float* __restrict__ nodes, float* __restrict__ xf){
    int row = blockIdx.x;                      // b*NAUG + i, 65536 blocks
    int t = threadIdx.x;
    int b = row >> 10, i = row & (NAUG - 1);
    float v = (i < NN) ? nodes[((size_t)b*NN + i)*DM + t] : 0.f;
    xf[(size_t)row*DM + t] = v;
}

// ---------------- SpMM: xt1 = (2/lam)*(lap @ x) - x, fp64 accum ----------------
__global__ __launch_bounds__(256)
void k_spmm(const u32* __restrict__ ents, const float* __restrict__ vals,
            const int* __restrict__ lens, const float* __restrict__ xf,
            const float* __restrict__ lam, float* __restrict__ xt1){
    int i = blockIdx.x;                        // 0..511
    int b = blockIdx.y;
    int t = threadIdx.x;
    int len = lens[b*NN + i];
    const u32*   er = ents + ((size_t)b*NN + i)*CAP;
    const float* ev = vals + ((size_t)b*NN + i)*CAP;
    const float* xb = xf + (size_t)b*NAUG*DM;
    double ar = 0.0, ai = 0.0;
    for (int e = 0; e < len; ++e){
        u32 en = er[e];
        double v = (double)ev[e];
        int j = en & 511;
        double xr = (double)xb[(size_t)j*DM + t];
        double xi = (double)xb[(size_t)(NN + j)*DM + t];
        if (en & 512u){ ar = fma(v, -xi, ar); ai = fma(v, xr, ai); }
        else          { ar = fma(v,  xr, ar); ai = fma(v, xi, ai); }
    }
    double alpha = 2.0 / (double)lam[0];
    size_t ro = ((size_t)b*NAUG + i)*DM + t;
    size_t io = ((size_t)b*NAUG + NN + i)*DM + t;
    xt1[ro] = (float)(alpha*ar - (double)xf[ro]);
    xt1[io] = (float)(alpha*ai - (double)xf[io]);
}

// ---------------- hybrid GEMM: s = x@w0 + xt1@w1 + bias ----------------
// fp32 fmaf within each 32-k block; block sums accumulated in fp64
__global__ __launch_bounds__(256)
void k_gemm32(const float* __restrict__ xf, const float* __restrict__ xt1,
              const float* __restrict__ w0, const float* __restrict__ w1,
              const float* __restrict__ bias, float* __restrict__ sOut){
    __shared__ float As[32][68];
    __shared__ float Bs[32][68];
    int m0 = blockIdx.y * 64;                  // flat row over BATCH*NAUG
    int n0 = blockIdx.x * 64;
    int tid = threadIdx.x;
    int tx = tid & 15, ty = tid >> 4;
    double acc[4][4];
#pragma unroll
    for (int r = 0; r < 4; ++r)
#pragma unroll
        for (int c = 0; c < 4; ++c) acc[r][c] = 0.0;
    for (int ph = 0; ph < 2; ++ph){
        const float* A = ph ? xt1 : xf;
        const float* W = ph ? w1 : w0;
        for (int k0 = 0; k0 < DM; k0 += 32){
#pragma unroll
            for (int l = 0; l < 2; ++l){
                int fi = tid + l*256;          // 512 float4 slots each
                int m  = fi >> 3, c4 = fi & 7; // A: 64 rows x 8 f4
                float4 g = *(const float4*)(A + ((size_t)(m0 + m))*DM + k0 + c4*4);
                As[c4*4+0][m] = g.x; As[c4*4+1][m] = g.y;
                As[c4*4+2][m] = g.z; As[c4*4+3][m] = g.w;
                int kk = fi >> 4, n4 = fi & 15;// B: 32 k x 16 f4
                float4 hh = *(const float4*)(W + ((size_t)(k0 + kk))*DM + n0 + n4*4);
                *(float4*)&Bs[kk][n4*4] = hh;
            }
            __syncthreads();
            float facc[4][4];
#pragma unroll
            for (int r = 0; r < 4; ++r)
#pragma unroll
                for (int c = 0; c < 4; ++c) facc[r][c] = 0.f;
#pragma unroll
            for (int kk = 0; kk < 32; ++kk){
                float4 a4 = *(const float4*)&As[kk][ty*4];
                float4 b4 = *(const float4*)&Bs[kk][tx*4];
                facc[0][0] = fmaf(a4.x, b4.x, facc[0][0]);
                facc[0][1] = fmaf(a4.x, b4.y, facc[0][1]);
                facc[0][2] = fmaf(a4.x, b4.z, facc[0][2]);
                facc[0][3] = fmaf(a4.x, b4.w, facc[0][3]);
                facc[1][0] = fmaf(a4.y, b4.x, facc[1][0]);
                facc[1][1] = fmaf(a4.y, b4.y, facc[1][1]);
                facc[1][2] = fmaf(a4.y, b4.z, facc[1][2]);
                facc[1][3] = fmaf(a4.y, b4.w, facc[1][3]);
                facc[2][0] = fmaf(a4.z, b4.x, facc[2][0]);
                facc[2][1] = fmaf(a4.z, b4.y, facc[2][1]);
                facc[2][2] = fmaf(a4.z, b4.z, facc[2][2]);
                facc[2][3] = fmaf(a4.z, b4.w, facc[2][3]);
                facc[3][0] = fmaf(a4.w, b4.x, facc[3][0]);
                facc[3][1] = fmaf(a4.w, b4.y, facc[3][1]);
                facc[3][2] = fmaf(a4.w, b4.z, facc[3][2]);
                facc[3][3] = fmaf(a4.w, b4.w, facc[3][3]);
            }
#pragma unroll
            for (int r = 0; r < 4; ++r)
#pragma unroll
                for (int c = 0; c < 4; ++c) acc[r][c] += (double)facc[r][c];
            __syncthreads();
        }
    }
    float4 bi = *(const float4*)(bias + n0 + tx*4);
#pragma unroll
    for (int r = 0; r < 4; ++r){
        float4 o;
        o.x = (float)(acc[r][0] + (double)bi.x);
        o.y = (float)(acc[r][1] + (double)bi.y);
        o.z = (float)(acc[r][2] + (double)bi.z);
        o.w = (float)(acc[r][3] + (double)bi.w);
        *(float4*)&sOut[((size_t)(m0 + ty*4 + r))*DM + n0 + tx*4] = o;
    }
}

// ---------------- combine: crelu -> next-layer x (fp32) or final output ----------
__global__ void k_combine32(const float* __restrict__ sIn, float* __restrict__ xf,
                            float* __restrict__ out, int isFinal){
    int i = blockIdx.x;                        // 0..511
    int b = blockIdx.y;
    int t = threadIdx.x;
    size_t ro = ((size_t)b*NAUG + i)*DM + t;
    size_t io = ((size_t)b*NAUG + NN + i)*DM + t;
    float re = sIn[ro], im = sIn[io];
    if (!(re >= 0.f)){ re = 0.f; im = 0.f; }   // (v.real >= 0) * v
    if (isFinal){
        out[((size_t)b*NN + i)*(2*DM) + t]      = re;
        out[((size_t)b*NN + i)*(2*DM) + DM + t] = im;
    } else {
        xf[ro] = re; xf[io] = im;
    }
}

// ---------------- host launch ----------------
extern "C" void kernel_launch(void* const* d_in, const int* in_sizes, int n_in,
                              void* d_out, int out_size, void* d_ws, size_t ws_size,
                              hipStream_t stream){
    const float* nodes   = (const float*)d_in[0];
    const int*   senders = (const int*)  d_in[1];
    const int*   recvs   = (const int*)  d_in[2];
    const int*   n_node  = (const int*)  d_in[3];
    const float* w00     = (const float*)d_in[4];
    const float* b00     = (const float*)d_in[5];
    const float* w10     = (const float*)d_in[6];
    const float* w01     = (const float*)d_in[7];
    const float* b01     = (const float*)d_in[8];
    const float* w11     = (const float*)d_in[9];
    char* ws = (char*)d_ws;
    u64*   adj    = (u64*)  (ws + OFF_ADJ);
    u64*   adjT   = (u64*)  (ws + OFF_ADJT);
    float* lam    = (float*)(ws + OFF_LAM);
    int*   lmax   = (int*)  (ws + OFF_LMX);
    uint2* pk2    = (uint2*)(ws + OFF_PK2);
    float* degInv = (float*)(ws + OFF_DEGI);
    int*   lens   = (int*)  (ws + OFF_LENS);
    u32*   ents   = (u32*)  (ws + OFF_ENTS);
    float* vals   = (float*)(ws + OFF_VALS);
    float* xf     = (float*)(ws + OFF_XF);
    float* xt1    = (float*)(ws + OFF_XT1);
    float* sBuf   = (float*)(ws + OFF_S);
    float* out    = (float*)d_out;

    // zero adj bitmasks + lambda/lmax + pk2 (zero-padding of the entry stream)
    hipMemsetAsync(ws + OFF_ADJ, 0, OFF_PK2 + SZ_PK2, stream);

    k_scatter<<<dim3(BATCH*NEDGE/256), dim3(256), 0, stream>>>(senders, recvs, adj, adjT);
    k_deg    <<<dim3(BATCH*NN/256),    dim3(256), 0, stream>>>(adj, adjT, degInv);
    k_build  <<<dim3(BATCH*NN/4),      dim3(256), 0, stream>>>(adj, adjT, degInv, n_node,
                                                               ents, vals, lens, pk2, lmax);
    k_lanczos<<<dim3(BATCH),           dim3(64),  0, stream>>>((const uint4*)pk2, lmax, lam);
    k_prep32 <<<dim3(BATCH*NAUG),      dim3(256), 0, stream>>>(nodes, xf);

    for (int layer = 0; layer < 2; ++layer){
        const float* w0 = layer ? w01 : w00;
        const float* w1 = layer ? w11 : w10;
        const float* bias = layer ? b01 : b00;
        k_spmm   <<<dim3(NN, BATCH),   dim3(256), 0, stream>>>(ents, vals, lens, xf, lam, xt1);
        k_gemm32 <<<dim3(DM/64, BATCH*NAUG/64), dim3(256), 0, stream>>>(xf, xt1, w0, w1, bias, sBuf);
        k_combine32<<<dim3(NN, BATCH), dim3(256), 0, stream>>>(sBuf, xf, out, layer);
    }
}

// Round 8
// 1518.056 us; speedup vs baseline: 2.6682x; 1.4780x over previous
//
#include <hip/hip_runtime.h>
#include <stdint.h>

typedef unsigned long long u64;
typedef unsigned int u32;
typedef unsigned short u16;

#define BATCH 64
#define NN    512
#define NAUG  1024
#define DM    256
#define NEDGE 4096
#define CAP   64
#define PK2   32       // packed entry-pair slots = CAP/2 (written)
#define PK2A  36       // allocated slots (pad stays zero -> unguarded prefetch)
#define LM    128      // Lanczos steps

// ---------------- workspace layout (bytes) ----------------
#define OFF_ADJ   ((size_t)0)
#define SZ_ADJ    ((size_t)BATCH*NN*8*8)                 // 2 MiB bitmask
#define OFF_ADJT  (OFF_ADJ + SZ_ADJ)
#define OFF_LAM   (OFF_ADJT + SZ_ADJ)                    // 4B lambda
#define OFF_LMX   (OFF_LAM + 64)                         // int lmax[64]
#define OFF_PK2   (OFF_LAM + 1024)
#define SZ_PK2    ((size_t)BATCH*PK2A*NN*16)             // 18.9 MB packed-pair lap stream
#define OFF_DEGI  (OFF_PK2 + SZ_PK2)
#define OFF_LENS  (OFF_DEGI + (size_t)BATCH*NN*4)
#define OFF_ENTS  (OFF_LENS + (size_t)BATCH*NN*4)
#define OFF_VALS  (OFF_ENTS + (size_t)BATCH*NN*CAP*4)
#define OFF_XF    (OFF_VALS + (size_t)BATCH*NN*CAP*4)    // x fp32 [b,1024,256]
#define OFF_XT1   (OFF_XF  + (size_t)BATCH*NAUG*DM*4)    // t1@x fp32
#define OFF_S     (OFF_XT1 + (size_t)BATCH*NAUG*DM*4)    // pre-relu sums fp32

// ---------------- adjacency scatter (bitmask) ----------------
__global__ void k_scatter(const int* __restrict__ senders, const int* __restrict__ receivers,
                          u64* __restrict__ adj, u64* __restrict__ adjT){
    int idx = blockIdx.x * 256 + threadIdx.x;          // BATCH*NEDGE threads
    int b = idx >> 12;
    int s = senders[idx];
    int r = receivers[idx];
    if (s >= 0){
        atomicOr(&adj [((size_t)b*NN + s)*8 + (r >> 6)], 1ull << (r & 63));
        atomicOr(&adjT[((size_t)b*NN + r)*8 + (s >> 6)], 1ull << (s & 63));
    }
}

// ---------------- degree (exact double 1/sqrt) ----------------
__global__ void k_deg(const u64* __restrict__ adj, const u64* __restrict__ adjT,
                      float* __restrict__ degInv){
    int idx = blockIdx.x * 256 + threadIdx.x;          // BATCH*NN threads
    const u64* a = adj  + (size_t)idx * 8;
    const u64* t = adjT + (size_t)idx * 8;
    int deg = 0;
#pragma unroll
    for (int w = 0; w < 8; ++w) deg += __popcll(a[w] | t[w]);
    degInv[idx] = (float)(1.0 / sqrt((double)(deg < 1 ? 1 : deg)));
}

// ---------------- build CSR + packed-pair stream (one wave per row) ----------
// CSR entry (k_spmm): bits[8:0]=col j, bit9=type; val fp32.
// pk2 entry (k_lanczos): uint2 {byteoff = j*8 + ty*4096, f32 val} — two entries
// packed per uint4 slot at [b][p>>1][i], half selected by p&1. Slots [32,36)
// are never written -> stay zero (harmless fma with 0) for unguarded prefetch.
__global__ __launch_bounds__(256)
void k_build(const u64* __restrict__ adj, const u64* __restrict__ adjT,
             const float* __restrict__ degInv, const int* __restrict__ n_node,
             u32* __restrict__ ents, float* __restrict__ vals, int* __restrict__ lens,
             uint2* __restrict__ pk2, int* __restrict__ lmax){
    int gw   = (blockIdx.x * 256 + threadIdx.x) >> 6;  // global wave = row id
    int lane = threadIdx.x & 63;
    int b = gw >> 9;
    int i = gw & (NN - 1);
    const u64* arow = adj  + ((size_t)b*NN + i)*8;
    const u64* trow = adjT + ((size_t)b*NN + i)*8;
    int wsel = lane >> 3, sh = (lane & 7) * 8;
    u32 ba = (u32)((arow[wsel] >> sh) & 0xFFull);
    u32 bt = (u32)((trow[wsel] >> sh) & 0xFFull);
    int nn_b = n_node[b];
    bool mi  = i < nn_b;
    float di = degInv[b*NN + i];
    int j0 = lane * 8;

    float vr_[8], vi_[8];
    int cnt = 0;
#pragma unroll
    for (int jj = 0; jj < 8; ++jj){
        int j = j0 + jj;
        int a = (ba >> jj) & 1, t = (bt >> jj) & 1;
        bool mm = mi && (j < nn_b);
        float c = di * degInv[b*NN + j];
        float vr = 0.f, vi = 0.f;
        if (j == i){
            if (mm) vr = 1.0f - (a ? c : 0.0f);        // diag: mask*(1 - selfloop*c)
        } else if (mm && ((a | t) != 0)){
            if (a & t)      vr = -c;                   // lap = -c
            else if (a)     vi = -c;                   // lap = -i*c
            else            vi =  c;                   // lap = +i*c
        }
        vr_[jj] = vr; vi_[jj] = vi;
        cnt += (vr != 0.f || vi != 0.f) ? 1 : 0;
    }
    // wave-wide exclusive scan of cnt
    int off = cnt;
#pragma unroll
    for (int d = 1; d < 64; d <<= 1){
        int nb = __shfl_up(off, d);
        if (lane >= d) off += nb;
    }
    int excl = off - cnt;
    int tot  = __shfl(off, 63);
    int p = excl;
    u32*   erow = ents + ((size_t)b*NN + i)*CAP;
    float* vrow = vals + ((size_t)b*NN + i)*CAP;
#pragma unroll
    for (int jj = 0; jj < 8; ++jj){
        float vr = vr_[jj], vi = vi_[jj];
        if (vr != 0.f || vi != 0.f){
            if (p < CAP){
                int ty = (vi != 0.f) ? 1 : 0;
                int j = j0 + jj;
                float v = ty ? vi : vr;
                erow[p] = (u32)j | ((u32)ty << 9);
                vrow[p] = v;
                size_t slot = ((size_t)b*PK2A + (p >> 1))*NN + i;
                pk2[slot*2 + (p & 1)] =
                    make_uint2((u32)((j << 3) + (ty << 12)), __float_as_uint(v));
            }
            p++;
        }
    }
    if (lane == 63){
        int tc = tot > CAP ? CAP : tot;
        lens[b*NN + i] = tc;
        atomicMax(&lmax[b], tc);
    }
}

// ---------------- Lanczos: ONE WAVE per graph, zero barriers ----------------
// Lane l owns rows {l+64r}. XY LDS: X[j]=(xr,xi) at byte 8j, Y[j]=(-xi,xr) at
// 4096+8j — entry type folded into its byte offset (ds_read_b64 + 2 fma).
// Triple-buffered stream prefetch with NO register copies: each load lands 2
// e-steps (~400+ cyc) before its use -> L2 latency fully hidden (R7's 1-deep
// rotation exposed a partial global-load stall at every e-step head).
// e-loop trip rounded to mult of 3; slots [ES,36) are zero -> harmless.
// beta = ||w - a*v - b*v0|| computed EXPLICITLY (Paige stability; R6 errata).
__global__ __launch_bounds__(64)
void k_lanczos(const uint4* __restrict__ pk2, const int* __restrict__ lmax,
               float* __restrict__ lam){
    int b = blockIdx.x, l = threadIdx.x;
    __shared__ float2 XY[2*NN];                        // X then Y
    __shared__ float alphS[LM], betS[LM];
    int Emax = lmax[b];
    int ES = (Emax + 1) >> 1;
    if (ES > PK2) ES = PK2;
    int ES3 = ((ES + 2) / 3) * 3;                      // mult of 3, <= 33
    const uint4* base = pk2 + (size_t)b*PK2A*NN;
    float xr[8], xi[8];
    float ss = 0.f;
#pragma unroll
    for (int r = 0; r < 8; ++r){
        u32 h = (u32)(l + 64*r) * 2654435761u + 0x9E3779B9u;
        h ^= h >> 16; h *= 0x85EBCA6Bu; h ^= h >> 13;
        xr[r] = (float)(h & 0xFFFF) * (1.f/65536.f) - 0.5f;
        h = h * 1664525u + 1013904223u;
        xi[r] = (float)(h & 0xFFFF) * (1.f/65536.f) - 0.5f;
        ss += xr[r]*xr[r] + xi[r]*xi[r];
    }
#pragma unroll
    for (int d = 1; d < 64; d <<= 1) ss += __shfl_xor(ss, d);
    float inv0 = 1.f / sqrtf(ss);
#pragma unroll
    for (int r = 0; r < 8; ++r){
        xr[r] *= inv0; xi[r] *= inv0;
        XY[l + 64*r]      = make_float2(xr[r], xi[r]);
        XY[NN + l + 64*r] = make_float2(-xi[r], xr[r]);
    }
    float v0r[8], v0i[8];
#pragma unroll
    for (int r = 0; r < 8; ++r){ v0r[r] = 0.f; v0i[r] = 0.f; }
    float betaPrev = 0.f;
    int mEff = LM;
    for (int j = 0; j < LM; ++j){
        float wr[8], wi[8];
#pragma unroll
        for (int r = 0; r < 8; ++r){ wr[r] = 0.f; wi[r] = 0.f; }
        uint4 qa[8], qb[8], qc[8];
#pragma unroll
        for (int r = 0; r < 8; ++r){
            qa[r] = base[(size_t)0*NN + 64*r + l];
            qb[r] = base[(size_t)1*NN + 64*r + l];
            qc[r] = base[(size_t)2*NN + 64*r + l];
        }
        for (int e = 0; e < ES3; e += 3){
            // compute(qa) for e, refill qa for e+3 (consumed 2 steps later)
#pragma unroll
            for (int r = 0; r < 8; ++r){
                float2 u0 = *(const float2*)((const char*)XY + qa[r].x);
                float g0 = __uint_as_float(qa[r].y);
                wr[r] = fmaf(g0, u0.x, wr[r]);
                wi[r] = fmaf(g0, u0.y, wi[r]);
                float2 u1 = *(const float2*)((const char*)XY + qa[r].z);
                float g1 = __uint_as_float(qa[r].w);
                wr[r] = fmaf(g1, u1.x, wr[r]);
                wi[r] = fmaf(g1, u1.y, wi[r]);
            }
#pragma unroll
            for (int r = 0; r < 8; ++r) qa[r] = base[(size_t)(e+3)*NN + 64*r + l];
#pragma unroll
            for (int r = 0; r < 8; ++r){
                float2 u0 = *(const float2*)((const char*)XY + qb[r].x);
                float g0 = __uint_as_float(qb[r].y);
                wr[r] = fmaf(g0, u0.x, wr[r]);
                wi[r] = fmaf(g0, u0.y, wi[r]);
                float2 u1 = *(const float2*)((const char*)XY + qb[r].z);
                float g1 = __uint_as_float(qb[r].w);
                wr[r] = fmaf(g1, u1.x, wr[r]);
                wi[r] = fmaf(g1, u1.y, wi[r]);
            }
#pragma unroll
            for (int r = 0; r < 8; ++r) qb[r] = base[(size_t)(e+4)*NN + 64*r + l];
#pragma unroll
            for (int r = 0; r < 8; ++r){
                float2 u0 = *(const float2*)((const char*)XY + qc[r].x);
                float g0 = __uint_as_float(qc[r].y);
                wr[r] = fmaf(g0, u0.x, wr[r]);
                wi[r] = fmaf(g0, u0.y, wi[r]);
                float2 u1 = *(const float2*)((const char*)XY + qc[r].z);
                float g1 = __uint_as_float(qc[r].w);
                wr[r] = fmaf(g1, u1.x, wr[r]);
                wi[r] = fmaf(g1, u1.y, wi[r]);
            }
#pragma unroll
            for (int r = 0; r < 8; ++r) qc[r] = base[(size_t)(e+5)*NN + 64*r + l];
        }
        // alpha = Re<v1, w>
        float pa = 0.f;
#pragma unroll
        for (int r = 0; r < 8; ++r) pa += xr[r]*wr[r] + xi[r]*wi[r];
#pragma unroll
        for (int d = 1; d < 64; d <<= 1) pa += __shfl_xor(pa, d);
        // w -= alpha*v1 + betaPrev*v0 ; beta = ||w|| (explicit, stable)
        float pb = 0.f;
#pragma unroll
        for (int r = 0; r < 8; ++r){
            wr[r] -= pa*xr[r] + betaPrev*v0r[r];
            wi[r] -= pa*xi[r] + betaPrev*v0i[r];
            pb += wr[r]*wr[r] + wi[r]*wi[r];
        }
#pragma unroll
        for (int d = 1; d < 64; d <<= 1) pb += __shfl_xor(pb, d);
        float bta = sqrtf(pb);
        if (l == 0){ alphS[j] = pa; betS[j] = bta; }
        if (bta < 1e-7f){ mEff = j + 1; break; }       // breakdown: invariant subspace
        float binv = 1.f / bta;
#pragma unroll
        for (int r = 0; r < 8; ++r){
            float nr = wr[r] * binv;
            float ni = wi[r] * binv;
            v0r[r] = xr[r]; v0i[r] = xi[r];
            xr[r] = nr; xi[r] = ni;
            XY[l + 64*r]      = make_float2(nr, ni);
            XY[NN + l + 64*r] = make_float2(-ni, nr);
        }
        betaPrev = bta;
    }
    // parallel-midpoint Sturm bisection: lane l tests mid_l; ballot brackets.
    int m = mEff;
    double lo = -0.5, hi = 2.5;                        // lap spectrum in [0,2]
    for (int sweep = 0; sweep < 5; ++sweep){
        double w = (hi - lo) * (1.0/65.0);
        double mid = lo + w * (double)(l + 1);
        int cnt = 0;
        double d = (double)alphS[0] - mid;
        if (d < 0.0) cnt++;
        for (int k = 1; k < m; ++k){
            if (d == 0.0) d = -1e-300;
            double bk = (double)betS[k-1];
            d = ((double)alphS[k] - mid) - bk*bk/d;
            if (d < 0.0) cnt++;
        }
        u64 mask = __ballot(cnt >= m);                 // mid above lam_max
        if (mask == 0ull){
            lo = lo + w * 64.0;
        } else {
            int L = __ffsll(mask) - 1;
            hi = lo + w * (double)(L + 1);
            lo = lo + w * (double)L;
        }
    }
    if (l == 0){
        float l1 = (float)hi;
        if (l1 < 0.f) l1 = 0.f;
        if (l1 > 2.0f) l1 = 2.0f;                      // normalized-lap bound
        atomicMax((u32*)lam, __float_as_uint(l1));
    }
}

// ---------------- prep: xf = [nodes; 0] fp32 aug-node-major ----------------
__global__ void k_prep32(const float* __restrict__ nodes, float* __restrict__ xf){
    int row = blockIdx.x;                      // b*NAUG + i, 65536 blocks
    int t = threadIdx.x;
    int b = row >> 10, i = row & (NAUG - 1);
    float v = (i < NN) ? nodes[((size_t)b*NN + i)*DM + t] : 0.f;
    xf[(size_t)row*DM + t] = v;
}

// ---------------- SpMM: xt1 = (2/lam)*(lap @ x) - x, fp64 accum ----------------
__global__ __launch_bounds__(256)
void k_spmm(const u32* __restrict__ ents, const float* __restrict__ vals,
            const int* __restrict__ lens, const float* __restrict__ xf,
            const float* __restrict__ lam, float* __restrict__ xt1){
    int i = blockIdx.x;                        // 0..511
    int b = blockIdx.y;
    int t = threadIdx.x;
    int len = lens[b*NN + i];
    const u32*   er = ents + ((size_t)b*NN + i)*CAP;
    const float* ev = vals + ((size_t)b*NN + i)*CAP;
    const float* xb = xf + (size_t)b*NAUG*DM;
    double ar = 0.0, ai = 0.0;
    for (int e = 0; e < len; ++e){
        u32 en = er[e];
        double v = (double)ev[e];
        int j = en & 511;
        double xr = (double)xb[(size_t)j*DM + t];
        double xi = (double)xb[(size_t)(NN + j)*DM + t];
        if (en & 512u){ ar = fma(v, -xi, ar); ai = fma(v, xr, ai); }
        else          { ar = fma(v,  xr, ar); ai = fma(v, xi, ai); }
    }
    double alpha = 2.0 / (double)lam[0];
    size_t ro = ((size_t)b*NAUG + i)*DM + t;
    size_t io = ((size_t)b*NAUG + NN + i)*DM + t;
    xt1[ro] = (float)(alpha*ar - (double)xf[ro]);
    xt1[io] = (float)(alpha*ai - (double)xf[io]);
}

// ---------------- hybrid GEMM: s = x@w0 + xt1@w1 + bias ----------------
// fp32 fmaf within each 32-k block; block sums accumulated in fp64
__global__ __launch_bounds__(256)
void k_gemm32(const float* __restrict__ xf, const float* __restrict__ xt1,
              const float* __restrict__ w0, const float* __restrict__ w1,
              const float* __restrict__ bias, float* __restrict__ sOut){
    __shared__ float As[32][68];
    __shared__ float Bs[32][68];
    int m0 = blockIdx.y * 64;                  // flat row over BATCH*NAUG
    int n0 = blockIdx.x * 64;
    int tid = threadIdx.x;
    int tx = tid & 15, ty = tid >> 4;
    double acc[4][4];
#pragma unroll
    for (int r = 0; r < 4; ++r)
#pragma unroll
        for (int c = 0; c < 4; ++c) acc[r][c] = 0.0;
    for (int ph = 0; ph < 2; ++ph){
        const float* A = ph ? xt1 : xf;
        const float* W = ph ? w1 : w0;
        for (int k0 = 0; k0 < DM; k0 += 32){
#pragma unroll
            for (int l = 0; l < 2; ++l){
                int fi = tid + l*256;          // 512 float4 slots each
                int m  = fi >> 3, c4 = fi & 7; // A: 64 rows x 8 f4
                float4 g = *(const float4*)(A + ((size_t)(m0 + m))*DM + k0 + c4*4);
                As[c4*4+0][m] = g.x; As[c4*4+1][m] = g.y;
                As[c4*4+2][m] = g.z; As[c4*4+3][m] = g.w;
                int kk = fi >> 4, n4 = fi & 15;// B: 32 k x 16 f4
                float4 hh = *(const float4*)(W + ((size_t)(k0 + kk))*DM + n0 + n4*4);
                *(float4*)&Bs[kk][n4*4] = hh;
            }
            __syncthreads();
            float facc[4][4];
#pragma unroll
            for (int r = 0; r < 4; ++r)
#pragma unroll
                for (int c = 0; c < 4; ++c) facc[r][c] = 0.f;
#pragma unroll
            for (int kk = 0; kk < 32; ++kk){
                float4 a4 = *(const float4*)&As[kk][ty*4];
                float4 b4 = *(const float4*)&Bs[kk][tx*4];
                facc[0][0] = fmaf(a4.x, b4.x, facc[0][0]);
                facc[0][1] = fmaf(a4.x, b4.y, facc[0][1]);
                facc[0][2] = fmaf(a4.x, b4.z, facc[0][2]);
                facc[0][3] = fmaf(a4.x, b4.w, facc[0][3]);
                facc[1][0] = fmaf(a4.y, b4.x, facc[1][0]);
                facc[1][1] = fmaf(a4.y, b4.y, facc[1][1]);
                facc[1][2] = fmaf(a4.y, b4.z, facc[1][2]);
                facc[1][3] = fmaf(a4.y, b4.w, facc[1][3]);
                facc[2][0] = fmaf(a4.z, b4.x, facc[2][0]);
                facc[2][1] = fmaf(a4.z, b4.y, facc[2][1]);
                facc[2][2] = fmaf(a4.z, b4.z, facc[2][2]);
                facc[2][3] = fmaf(a4.z, b4.w, facc[2][3]);
                facc[3][0] = fmaf(a4.w, b4.x, facc[3][0]);
                facc[3][1] = fmaf(a4.w, b4.y, facc[3][1]);
                facc[3][2] = fmaf(a4.w, b4.z, facc[3][2]);
                facc[3][3] = fmaf(a4.w, b4.w, facc[3][3]);
            }
#pragma unroll
            for (int r = 0; r < 4; ++r)
#pragma unroll
                for (int c = 0; c < 4; ++c) acc[r][c] += (double)facc[r][c];
            __syncthreads();
        }
    }
    float4 bi = *(const float4*)(bias + n0 + tx*4);
#pragma unroll
    for (int r = 0; r < 4; ++r){
        float4 o;
        o.x = (float)(acc[r][0] + (double)bi.x);
        o.y = (float)(acc[r][1] + (double)bi.y);
        o.z = (float)(acc[r][2] + (double)bi.z);
        o.w = (float)(acc[r][3] + (double)bi.w);
        *(float4*)&sOut[((size_t)(m0 + ty*4 + r))*DM + n0 + tx*4] = o;
    }
}

// ---------------- combine: crelu -> next-layer x (fp32) or final output ----------
__global__ void k_combine32(const float* __restrict__ sIn, float* __restrict__ xf,
                            float* __restrict__ out, int isFinal){
    int i = blockIdx.x;                        // 0..511
    int b = blockIdx.y;
    int t = threadIdx.x;
    size_t ro = ((size_t)b*NAUG + i)*DM + t;
    size_t io = ((size_t)b*NAUG + NN + i)*DM + t;
    float re = sIn[ro], im = sIn[io];
    if (!(re >= 0.f)){ re = 0.f; im = 0.f; }   // (v.real >= 0) * v
    if (isFinal){
        out[((size_t)b*NN + i)*(2*DM) + t]      = re;
        out[((size_t)b*NN + i)*(2*DM) + DM + t] = im;
    } else {
        xf[ro] = re; xf[io] = im;
    }
}

// ---------------- host launch ----------------
extern "C" void kernel_launch(void* const* d_in, const int* in_sizes, int n_in,
                              void* d_out, int out_size, void* d_ws, size_t ws_size,
                              hipStream_t stream){
    const float* nodes   = (const float*)d_in[0];
    const int*   senders = (const int*)  d_in[1];
    const int*   recvs   = (const int*)  d_in[2];
    const int*   n_node  = (const int*)  d_in[3];
    const float* w00     = (const float*)d_in[4];
    const float* b00     = (const float*)d_in[5];
    const float* w10     = (const float*)d_in[6];
    const float* w01     = (const float*)d_in[7];
    const float* b01     = (const float*)d_in[8];
    const float* w11     = (const float*)d_in[9];
    char* ws = (char*)d_ws;
    u64*   adj    = (u64*)  (ws + OFF_ADJ);
    u64*   adjT   = (u64*)  (ws + OFF_ADJT);
    float* lam    = (float*)(ws + OFF_LAM);
    int*   lmax   = (int*)  (ws + OFF_LMX);
    uint2* pk2    = (uint2*)(ws + OFF_PK2);
    float* degInv = (float*)(ws + OFF_DEGI);
    int*   lens   = (int*)  (ws + OFF_LENS);
    u32*   ents   = (u32*)  (ws + OFF_ENTS);
    float* vals   = (float*)(ws + OFF_VALS);
    float* xf     = (float*)(ws + OFF_XF);
    float* xt1    = (float*)(ws + OFF_XT1);
    float* sBuf   = (float*)(ws + OFF_S);
    float* out    = (float*)d_out;

    // zero adj bitmasks + lambda/lmax + pk2 (zero-padding of the entry stream)
    hipMemsetAsync(ws + OFF_ADJ, 0, OFF_PK2 + SZ_PK2, stream);

    k_scatter<<<dim3(BATCH*NEDGE/256), dim3(256), 0, stream>>>(senders, recvs, adj, adjT);
    k_deg    <<<dim3(BATCH*NN/256),    dim3(256), 0, stream>>>(adj, adjT, degInv);
    k_build  <<<dim3(BATCH*NN/4),      dim3(256), 0, stream>>>(adj, adjT, degInv, n_node,
                                                               ents, vals, lens, pk2, lmax);
    k_lanczos<<<dim3(BATCH),           dim3(64),  0, stream>>>((const uint4*)pk2, lmax, lam);
    k_prep32 <<<dim3(BATCH*NAUG),      dim3(256), 0, stream>>>(nodes, xf);

    for (int layer = 0; layer < 2; ++layer){
        const float* w0 = layer ? w01 : w00;
        const float* w1 = layer ? w11 : w10;
        const float* bias = layer ? b01 : b00;
        k_spmm   <<<dim3(NN, BATCH),   dim3(256), 0, stream>>>(ents, vals, lens, xf, lam, xt1);
        k_gemm32 <<<dim3(DM/64, BATCH*NAUG/64), dim3(256), 0, stream>>>(xf, xt1, w0, w1, bias, sBuf);
        k_combine32<<<dim3(NN, BATCH), dim3(256), 0, stream>>>(sBuf, xf, out, layer);
    }
}

// Round 10
// 1359.897 us; speedup vs baseline: 2.9785x; 1.1163x over previous
//
#include <hip/hip_runtime.h>
#include <stdint.h>

typedef unsigned long long u64;
typedef unsigned int u32;
typedef unsigned short u16;

#define BATCH 64
#define NN    512
#define NAUG  1024
#define DM    256
#define NEDGE 4096
#define CAP   64
#define PK2   32       // packed entry-pair slots = CAP/2 (written)
#define PK2A  36       // allocated slots (pad stays zero -> unguarded prefetch)
#define LM    128      // Lanczos steps (96 under-converged: R9 absmax 0.342)
#define RG    4        // row-groups per wave (2 waves x 4 = 8 groups of 64 rows)

// ---------------- workspace layout (bytes) ----------------
#define OFF_ADJ   ((size_t)0)
#define SZ_ADJ    ((size_t)BATCH*NN*8*8)                 // 2 MiB bitmask
#define OFF_ADJT  (OFF_ADJ + SZ_ADJ)
#define OFF_LAM   (OFF_ADJT + SZ_ADJ)                    // 4B lambda
#define OFF_LMX   (OFF_LAM + 64)                         // int lmax[64]
#define OFF_PK2   (OFF_LAM + 1024)
#define SZ_PK2    ((size_t)BATCH*PK2A*NN*16)             // 18.9 MB packed-pair lap stream
#define OFF_DEGI  (OFF_PK2 + SZ_PK2)
#define OFF_LENS  (OFF_DEGI + (size_t)BATCH*NN*4)
#define OFF_ENTS  (OFF_LENS + (size_t)BATCH*NN*4)
#define OFF_VALS  (OFF_ENTS + (size_t)BATCH*NN*CAP*4)
#define OFF_XF    (OFF_VALS + (size_t)BATCH*NN*CAP*4)    // x fp32 [b,1024,256]
#define OFF_XT1   (OFF_XF  + (size_t)BATCH*NAUG*DM*4)    // t1@x fp32
#define OFF_S     (OFF_XT1 + (size_t)BATCH*NAUG*DM*4)    // pre-relu sums fp32

// ---------------- adjacency scatter (bitmask) ----------------
__global__ void k_scatter(const int* __restrict__ senders, const int* __restrict__ receivers,
                          u64* __restrict__ adj, u64* __restrict__ adjT){
    int idx = blockIdx.x * 256 + threadIdx.x;          // BATCH*NEDGE threads
    int b = idx >> 12;
    int s = senders[idx];
    int r = receivers[idx];
    if (s >= 0){
        atomicOr(&adj [((size_t)b*NN + s)*8 + (r >> 6)], 1ull << (r & 63));
        atomicOr(&adjT[((size_t)b*NN + r)*8 + (s >> 6)], 1ull << (s & 63));
    }
}

// ---------------- degree (exact double 1/sqrt) ----------------
__global__ void k_deg(const u64* __restrict__ adj, const u64* __restrict__ adjT,
                      float* __restrict__ degInv){
    int idx = blockIdx.x * 256 + threadIdx.x;          // BATCH*NN threads
    const u64* a = adj  + (size_t)idx * 8;
    const u64* t = adjT + (size_t)idx * 8;
    int deg = 0;
#pragma unroll
    for (int w = 0; w < 8; ++w) deg += __popcll(a[w] | t[w]);
    degInv[idx] = (float)(1.0 / sqrt((double)(deg < 1 ? 1 : deg)));
}

// ---------------- build CSR + packed-pair stream (one wave per row) ----------
// CSR entry (k_spmm): bits[8:0]=col j, bit9=type; val fp32.
// pk2 entry (k_lanczos): uint2 {byteoff = j*8 + ty*4096, f32 val} — two entries
// packed per uint4 slot at [b][p>>1][i], half selected by p&1. Slots [32,36)
// are never written -> stay zero (harmless fma with 0) for unguarded prefetch.
__global__ __launch_bounds__(256)
void k_build(const u64* __restrict__ adj, const u64* __restrict__ adjT,
             const float* __restrict__ degInv, const int* __restrict__ n_node,
             u32* __restrict__ ents, float* __restrict__ vals, int* __restrict__ lens,
             uint2* __restrict__ pk2, int* __restrict__ lmax){
    int gw   = (blockIdx.x * 256 + threadIdx.x) >> 6;  // global wave = row id
    int lane = threadIdx.x & 63;
    int b = gw >> 9;
    int i = gw & (NN - 1);
    const u64* arow = adj  + ((size_t)b*NN + i)*8;
    const u64* trow = adjT + ((size_t)b*NN + i)*8;
    int wsel = lane >> 3, sh = (lane & 7) * 8;
    u32 ba = (u32)((arow[wsel] >> sh) & 0xFFull);
    u32 bt = (u32)((trow[wsel] >> sh) & 0xFFull);
    int nn_b = n_node[b];
    bool mi  = i < nn_b;
    float di = degInv[b*NN + i];
    int j0 = lane * 8;

    float vr_[8], vi_[8];
    int cnt = 0;
#pragma unroll
    for (int jj = 0; jj < 8; ++jj){
        int j = j0 + jj;
        int a = (ba >> jj) & 1, t = (bt >> jj) & 1;
        bool mm = mi && (j < nn_b);
        float c = di * degInv[b*NN + j];
        float vr = 0.f, vi = 0.f;
        if (j == i){
            if (mm) vr = 1.0f - (a ? c : 0.0f);        // diag: mask*(1 - selfloop*c)
        } else if (mm && ((a | t) != 0)){
            if (a & t)      vr = -c;                   // lap = -c
            else if (a)     vi = -c;                   // lap = -i*c
            else            vi =  c;                   // lap = +i*c
        }
        vr_[jj] = vr; vi_[jj] = vi;
        cnt += (vr != 0.f || vi != 0.f) ? 1 : 0;
    }
    // wave-wide exclusive scan of cnt
    int off = cnt;
#pragma unroll
    for (int d = 1; d < 64; d <<= 1){
        int nb = __shfl_up(off, d);
        if (lane >= d) off += nb;
    }
    int excl = off - cnt;
    int tot  = __shfl(off, 63);
    int p = excl;
    u32*   erow = ents + ((size_t)b*NN + i)*CAP;
    float* vrow = vals + ((size_t)b*NN + i)*CAP;
#pragma unroll
    for (int jj = 0; jj < 8; ++jj){
        float vr = vr_[jj], vi = vi_[jj];
        if (vr != 0.f || vi != 0.f){
            if (p < CAP){
                int ty = (vi != 0.f) ? 1 : 0;
                int j = j0 + jj;
                float v = ty ? vi : vr;
                erow[p] = (u32)j | ((u32)ty << 9);
                vrow[p] = v;
                size_t slot = ((size_t)b*PK2A + (p >> 1))*NN + i;
                pk2[slot*2 + (p & 1)] =
                    make_uint2((u32)((j << 3) + (ty << 12)), __float_as_uint(v));
            }
            p++;
        }
    }
    if (lane == 63){
        int tc = tot > CAP ? CAP : tot;
        lens[b*NN + i] = tc;
        atomicMax(&lmax[b], tc);
    }
}

// ---------------- Lanczos: TWO waves per graph, 3 barriers/iter ----------------
// Wave w owns row-groups r in [4w, 4w+4); lane l owns rows 64*(4w+r)+l.
// XY LDS: X[j]=(xr,xi) at byte 8j, Y[j]=(-xi,xr) at 4096+8j — entry type folded
// into its byte offset (ds_read_b64 + 2 fma). Triple-buffered stream prefetch
// (no register copies; loads land 2 e-steps early -> L2 latency hidden).
// Cross-wave reductions: in-wave butterfly -> 1 LDS float per wave -> barrier
// -> both waves sum 2 floats. LM=128 and 5 Sturm sweeps restore R8 numerics
// exactly (R9's LM=96 under-converged the worst graph: absmax 0.342).
// beta = ||w - a*v - b*v0|| computed EXPLICITLY (Paige stability; R6 errata).
__global__ __launch_bounds__(128)
void k_lanczos(const uint4* __restrict__ pk2, const int* __restrict__ lmax,
               float* __restrict__ lam){
    int b = blockIdx.x;
    int tid = threadIdx.x;
    int w = tid >> 6, l = tid & 63;
    __shared__ float2 XY[2*NN];                        // X then Y
    __shared__ float alphS[LM], betS[LM];
    __shared__ float redA[2], redB[2];
    int Emax = lmax[b];
    int ES = (Emax + 1) >> 1;
    if (ES > PK2) ES = PK2;
    int ES3 = ((ES + 2) / 3) * 3;                      // mult of 3, <= 33
    const uint4* base = pk2 + (size_t)b*PK2A*NN;
    int r0 = RG * w;                                   // this wave's first r-group
    float xr[RG], xi[RG];
    float ss = 0.f;
#pragma unroll
    for (int r = 0; r < RG; ++r){
        int row = (r0 + r)*64 + l;
        u32 h = (u32)row * 2654435761u + 0x9E3779B9u;
        h ^= h >> 16; h *= 0x85EBCA6Bu; h ^= h >> 13;
        xr[r] = (float)(h & 0xFFFF) * (1.f/65536.f) - 0.5f;
        h = h * 1664525u + 1013904223u;
        xi[r] = (float)(h & 0xFFFF) * (1.f/65536.f) - 0.5f;
        ss += xr[r]*xr[r] + xi[r]*xi[r];
    }
#pragma unroll
    for (int d = 1; d < 64; d <<= 1) ss += __shfl_xor(ss, d);
    if (l == 0) redA[w] = ss;
    __syncthreads();
    float inv0 = 1.f / sqrtf(redA[0] + redA[1]);
#pragma unroll
    for (int r = 0; r < RG; ++r){
        xr[r] *= inv0; xi[r] *= inv0;
        int row = (r0 + r)*64 + l;
        XY[row]      = make_float2(xr[r], xi[r]);
        XY[NN + row] = make_float2(-xi[r], xr[r]);
    }
    __syncthreads();
    float v0r[RG], v0i[RG];
#pragma unroll
    for (int r = 0; r < RG; ++r){ v0r[r] = 0.f; v0i[r] = 0.f; }
    float betaPrev = 0.f;
    int mEff = LM;
    for (int j = 0; j < LM; ++j){
        float wr[RG], wi[RG];
#pragma unroll
        for (int r = 0; r < RG; ++r){ wr[r] = 0.f; wi[r] = 0.f; }
        uint4 qa[RG], qb[RG], qc[RG];
#pragma unroll
        for (int r = 0; r < RG; ++r){
            qa[r] = base[(size_t)0*NN + (r0 + r)*64 + l];
            qb[r] = base[(size_t)1*NN + (r0 + r)*64 + l];
            qc[r] = base[(size_t)2*NN + (r0 + r)*64 + l];
        }
        for (int e = 0; e < ES3; e += 3){
#pragma unroll
            for (int r = 0; r < RG; ++r){
                float2 u0 = *(const float2*)((const char*)XY + qa[r].x);
                float g0 = __uint_as_float(qa[r].y);
                wr[r] = fmaf(g0, u0.x, wr[r]);
                wi[r] = fmaf(g0, u0.y, wi[r]);
                float2 u1 = *(const float2*)((const char*)XY + qa[r].z);
                float g1 = __uint_as_float(qa[r].w);
                wr[r] = fmaf(g1, u1.x, wr[r]);
                wi[r] = fmaf(g1, u1.y, wi[r]);
            }
#pragma unroll
            for (int r = 0; r < RG; ++r) qa[r] = base[(size_t)(e+3)*NN + (r0 + r)*64 + l];
#pragma unroll
            for (int r = 0; r < RG; ++r){
                float2 u0 = *(const float2*)((const char*)XY + qb[r].x);
                float g0 = __uint_as_float(qb[r].y);
                wr[r] = fmaf(g0, u0.x, wr[r]);
                wi[r] = fmaf(g0, u0.y, wi[r]);
                float2 u1 = *(const float2*)((const char*)XY + qb[r].z);
                float g1 = __uint_as_float(qb[r].w);
                wr[r] = fmaf(g1, u1.x, wr[r]);
                wi[r] = fmaf(g1, u1.y, wi[r]);
            }
#pragma unroll
            for (int r = 0; r < RG; ++r) qb[r] = base[(size_t)(e+4)*NN + (r0 + r)*64 + l];
#pragma unroll
            for (int r = 0; r < RG; ++r){
                float2 u0 = *(const float2*)((const char*)XY + qc[r].x);
                float g0 = __uint_as_float(qc[r].y);
                wr[r] = fmaf(g0, u0.x, wr[r]);
                wi[r] = fmaf(g0, u0.y, wi[r]);
                float2 u1 = *(const float2*)((const char*)XY + qc[r].z);
                float g1 = __uint_as_float(qc[r].w);
                wr[r] = fmaf(g1, u1.x, wr[r]);
                wi[r] = fmaf(g1, u1.y, wi[r]);
            }
#pragma unroll
            for (int r = 0; r < RG; ++r) qc[r] = base[(size_t)(e+5)*NN + (r0 + r)*64 + l];
        }
        // alpha = Re<v1, w> : in-wave butterfly, then cross-wave via LDS
        float pa = 0.f;
#pragma unroll
        for (int r = 0; r < RG; ++r) pa += xr[r]*wr[r] + xi[r]*wi[r];
#pragma unroll
        for (int d = 1; d < 64; d <<= 1) pa += __shfl_xor(pa, d);
        if (l == 0) redA[w] = pa;
        __syncthreads();
        float paF = redA[0] + redA[1];
        // w -= alpha*v1 + betaPrev*v0 ; beta = ||w|| (explicit, stable)
        float pb = 0.f;
#pragma unroll
        for (int r = 0; r < RG; ++r){
            wr[r] -= paF*xr[r] + betaPrev*v0r[r];
            wi[r] -= paF*xi[r] + betaPrev*v0i[r];
            pb += wr[r]*wr[r] + wi[r]*wi[r];
        }
#pragma unroll
        for (int d = 1; d < 64; d <<= 1) pb += __shfl_xor(pb, d);
        if (l == 0) redB[w] = pb;
        __syncthreads();
        float pbF = redB[0] + redB[1];
        float bta = sqrtf(pbF);
        if (w == 0 && l == 0){ alphS[j] = paF; betS[j] = bta; }
        if (pbF < 1e-14f){ mEff = j + 1; break; }      // uniform: pbF same both waves
        float binv = 1.f / bta;
#pragma unroll
        for (int r = 0; r < RG; ++r){
            float nr = wr[r] * binv;
            float ni = wi[r] * binv;
            v0r[r] = xr[r]; v0i[r] = xi[r];
            xr[r] = nr; xi[r] = ni;
            int row = (r0 + r)*64 + l;
            XY[row]      = make_float2(nr, ni);
            XY[NN + row] = make_float2(-ni, nr);
        }
        __syncthreads();                               // X visible before next e-loop
        betaPrev = bta;
    }
    // parallel-midpoint Sturm bisection on wave 0: lane l tests mid_l; ballot.
    if (w == 0){
        int m = mEff;
        double lo = -0.5, hi = 2.5;                    // lap spectrum in [0,2]
        for (int sweep = 0; sweep < 5; ++sweep){
            double wd = (hi - lo) * (1.0/65.0);
            double mid = lo + wd * (double)(l + 1);
            int cnt = 0;
            double d = (double)alphS[0] - mid;
            if (d < 0.0) cnt++;
            for (int k = 1; k < m; ++k){
                if (d == 0.0) d = -1e-300;
                double bk = (double)betS[k-1];
                d = ((double)alphS[k] - mid) - bk*bk/d;
                if (d < 0.0) cnt++;
            }
            u64 mask = __ballot(cnt >= m);             // mid above lam_max
            if (mask == 0ull){
                lo = lo + wd * 64.0;
            } else {
                int L = __ffsll(mask) - 1;
                hi = lo + wd * (double)(L + 1);
                lo = lo + wd * (double)L;
            }
        }
        if (l == 0){
            float l1 = (float)hi;
            if (l1 < 0.f) l1 = 0.f;
            if (l1 > 2.0f) l1 = 2.0f;                  // normalized-lap bound
            atomicMax((u32*)lam, __float_as_uint(l1));
        }
    }
}

// ---------------- prep: xf = [nodes; 0] fp32 aug-node-major ----------------
__global__ void k_prep32(const float* __restrict__ nodes, float* __restrict__ xf){
    int row = blockIdx.x;                      // b*NAUG + i, 65536 blocks
    int t = threadIdx.x;
    int b = row >> 10, i = row & (NAUG - 1);
    float v = (i < NN) ? nodes[((size_t)b*NN + i)*DM + t] : 0.f;
    xf[(size_t)row*DM + t] = v;
}

// ---------------- SpMM: xt1 = (2/lam)*(lap @ x) - x, fp64 accum ----------------
__global__ __launch_bounds__(256)
void k_spmm(const u32* __restrict__ ents, const float* __restrict__ vals,
            const int* __restrict__ lens, const float* __restrict__ xf,
            const float* __restrict__ lam, float* __restrict__ xt1){
    int i = blockIdx.x;                        // 0..511
    int b = blockIdx.y;
    int t = threadIdx.x;
    int len = lens[b*NN + i];
    const u32*   er = ents + ((size_t)b*NN + i)*CAP;
    const float* ev = vals + ((size_t)b*NN + i)*CAP;
    const float* xb = xf + (size_t)b*NAUG*DM;
    double ar = 0.0, ai = 0.0;
    for (int e = 0; e < len; ++e){
        u32 en = er[e];
        double v = (double)ev[e];
        int j = en & 511;
        double xr = (double)xb[(size_t)j*DM + t];
        double xi = (double)xb[(size_t)(NN + j)*DM + t];
        if (en & 512u){ ar = fma(v, -xi, ar); ai = fma(v, xr, ai); }
        else          { ar = fma(v,  xr, ar); ai = fma(v, xi, ai); }
    }
    double alpha = 2.0 / (double)lam[0];
    size_t ro = ((size_t)b*NAUG + i)*DM + t;
    size_t io = ((size_t)b*NAUG + NN + i)*DM + t;
    xt1[ro] = (float)(alpha*ar - (double)xf[ro]);
    xt1[io] = (float)(alpha*ai - (double)xf[io]);
}

// ---------------- hybrid GEMM: s = x@w0 + xt1@w1 + bias ----------------
// fp32 fmaf within each 32-k block; block sums accumulated in fp64
__global__ __launch_bounds__(256)
void k_gemm32(const float* __restrict__ xf, const float* __restrict__ xt1,
              const float* __restrict__ w0, const float* __restrict__ w1,
              const float* __restrict__ bias, float* __restrict__ sOut){
    __shared__ float As[32][68];
    __shared__ float Bs[32][68];
    int m0 = blockIdx.y * 64;                  // flat row over BATCH*NAUG
    int n0 = blockIdx.x * 64;
    int tid = threadIdx.x;
    int tx = tid & 15, ty = tid >> 4;
    double acc[4][4];
#pragma unroll
    for (int r = 0; r < 4; ++r)
#pragma unroll
        for (int c = 0; c < 4; ++c) acc[r][c] = 0.0;
    for (int ph = 0; ph < 2; ++ph){
        const float* A = ph ? xt1 : xf;
        const float* W = ph ? w1 : w0;
        for (int k0 = 0; k0 < DM; k0 += 32){
#pragma unroll
            for (int l = 0; l < 2; ++l){
                int fi = tid + l*256;          // 512 float4 slots each
                int m  = fi >> 3, c4 = fi & 7; // A: 64 rows x 8 f4
                float4 g = *(const float4*)(A + ((size_t)(m0 + m))*DM + k0 + c4*4);
                As[c4*4+0][m] = g.x; As[c4*4+1][m] = g.y;
                As[c4*4+2][m] = g.z; As[c4*4+3][m] = g.w;
                int kk = fi >> 4, n4 = fi & 15;// B: 32 k x 16 f4
                float4 hh = *(const float4*)(W + ((size_t)(k0 + kk))*DM + n0 + n4*4);
                *(float4*)&Bs[kk][n4*4] = hh;
            }
            __syncthreads();
            float facc[4][4];
#pragma unroll
            for (int r = 0; r < 4; ++r)
#pragma unroll
                for (int c = 0; c < 4; ++c) facc[r][c] = 0.f;
#pragma unroll
            for (int kk = 0; kk < 32; ++kk){
                float4 a4 = *(const float4*)&As[kk][ty*4];
                float4 b4 = *(const float4*)&Bs[kk][tx*4];
                facc[0][0] = fmaf(a4.x, b4.x, facc[0][0]);
                facc[0][1] = fmaf(a4.x, b4.y, facc[0][1]);
                facc[0][2] = fmaf(a4.x, b4.z, facc[0][2]);
                facc[0][3] = fmaf(a4.x, b4.w, facc[0][3]);
                facc[1][0] = fmaf(a4.y, b4.x, facc[1][0]);
                facc[1][1] = fmaf(a4.y, b4.y, facc[1][1]);
                facc[1][2] = fmaf(a4.y, b4.z, facc[1][2]);
                facc[1][3] = fmaf(a4.y, b4.w, facc[1][3]);
                facc[2][0] = fmaf(a4.z, b4.x, facc[2][0]);
                facc[2][1] = fmaf(a4.z, b4.y, facc[2][1]);
                facc[2][2] = fmaf(a4.z, b4.z, facc[2][2]);
                facc[2][3] = fmaf(a4.z, b4.w, facc[2][3]);
                facc[3][0] = fmaf(a4.w, b4.x, facc[3][0]);
                facc[3][1] = fmaf(a4.w, b4.y, facc[3][1]);
                facc[3][2] = fmaf(a4.w, b4.z, facc[3][2]);
                facc[3][3] = fmaf(a4.w, b4.w, facc[3][3]);
            }
#pragma unroll
            for (int r = 0; r < 4; ++r)
#pragma unroll
                for (int c = 0; c < 4; ++c) acc[r][c] += (double)facc[r][c];
            __syncthreads();
        }
    }
    float4 bi = *(const float4*)(bias + n0 + tx*4);
#pragma unroll
    for (int r = 0; r < 4; ++r){
        float4 o;
        o.x = (float)(acc[r][0] + (double)bi.x);
        o.y = (float)(acc[r][1] + (double)bi.y);
        o.z = (float)(acc[r][2] + (double)bi.z);
        o.w = (float)(acc[r][3] + (double)bi.w);
        *(float4*)&sOut[((size_t)(m0 + ty*4 + r))*DM + n0 + tx*4] = o;
    }
}

// ---------------- combine: crelu -> next-layer x (fp32) or final output ----------
__global__ void k_combine32(const float* __restrict__ sIn, float* __restrict__ xf,
                            float* __restrict__ out, int isFinal){
    int i = blockIdx.x;                        // 0..511
    int b = blockIdx.y;
    int t = threadIdx.x;
    size_t ro = ((size_t)b*NAUG + i)*DM + t;
    size_t io = ((size_t)b*NAUG + NN + i)*DM + t;
    float re = sIn[ro], im = sIn[io];
    if (!(re >= 0.f)){ re = 0.f; im = 0.f; }   // (v.real >= 0) * v
    if (isFinal){
        out[((size_t)b*NN + i)*(2*DM) + t]      = re;
        out[((size_t)b*NN + i)*(2*DM) + DM + t] = im;
    } else {
        xf[ro] = re; xf[io] = im;
    }
}

// ---------------- host launch ----------------
extern "C" void kernel_launch(void* const* d_in, const int* in_sizes, int n_in,
                              void* d_out, int out_size, void* d_ws, size_t ws_size,
                              hipStream_t stream){
    const float* nodes   = (const float*)d_in[0];
    const int*   senders = (const int*)  d_in[1];
    const int*   recvs   = (const int*)  d_in[2];
    const int*   n_node  = (const int*)  d_in[3];
    const float* w00     = (const float*)d_in[4];
    const float* b00     = (const float*)d_in[5];
    const float* w10     = (const float*)d_in[6];
    const float* w01     = (const float*)d_in[7];
    const float* b01     = (const float*)d_in[8];
    const float* w11     = (const float*)d_in[9];
    char* ws = (char*)d_ws;
    u64*   adj    = (u64*)  (ws + OFF_ADJ);
    u64*   adjT   = (u64*)  (ws + OFF_ADJT);
    float* lam    = (float*)(ws + OFF_LAM);
    int*   lmax   = (int*)  (ws + OFF_LMX);
    uint2* pk2    = (uint2*)(ws + OFF_PK2);
    float* degInv = (float*)(ws + OFF_DEGI);
    int*   lens   = (int*)  (ws + OFF_LENS);
    u32*   ents   = (u32*)  (ws + OFF_ENTS);
    float* vals   = (float*)(ws + OFF_VALS);
    float* xf     = (float*)(ws + OFF_XF);
    float* xt1    = (float*)(ws + OFF_XT1);
    float* sBuf   = (float*)(ws + OFF_S);
    float* out    = (float*)d_out;

    // zero adj bitmasks + lambda/lmax + pk2 (zero-padding of the entry stream)
    hipMemsetAsync(ws + OFF_ADJ, 0, OFF_PK2 + SZ_PK2, stream);

    k_scatter<<<dim3(BATCH*NEDGE/256), dim3(256), 0, stream>>>(senders, recvs, adj, adjT);
    k_deg    <<<dim3(BATCH*NN/256),    dim3(256), 0, stream>>>(adj, adjT, degInv);
    k_build  <<<dim3(BATCH*NN/4),      dim3(256), 0, stream>>>(adj, adjT, degInv, n_node,
                                                               ents, vals, lens, pk2, lmax);
    k_lanczos<<<dim3(BATCH),           dim3(128), 0, stream>>>((const uint4*)pk2, lmax, lam);
    k_prep32 <<<dim3(BATCH*NAUG),      dim3(256), 0, stream>>>(nodes, xf);

    for (int layer = 0; layer < 2; ++layer){
        const float* w0 = layer ? w01 : w00;
        const float* w1 = layer ? w11 : w10;
        const float* bias = layer ? b01 : b00;
        k_spmm   <<<dim3(NN, BATCH),   dim3(256), 0, stream>>>(ents, vals, lens, xf, lam, xt1);
        k_gemm32 <<<dim3(DM/64, BATCH*NAUG/64), dim3(256), 0, stream>>>(xf, xt1, w0, w1, bias, sBuf);
        k_combine32<<<dim3(NN, BATCH), dim3(256), 0, stream>>>(sBuf, xf, out, layer);
    }
}